// Round 6
// baseline (531.525 us; speedup 1.0000x reference)
//
#include <hip/hip_runtime.h>

#define N_NODES 50000
#define N_EDGES 800000
#define ETOT (N_EDGES + N_NODES)   // 850000
#define G_GRAPHS 256
#define F_IN 128
#define H1 12
#define D1 32
#define C1 (H1*D1)   // 384
#define C2 64
#define NEG 0.2f
#define SCAN_B 1024
#define NBLK_SCAN ((N_NODES + SCAN_B - 1)/SCAN_B)   // 49

using bf16x8  = __attribute__((ext_vector_type(8))) short;
using ushort8 = __attribute__((ext_vector_type(8))) unsigned short;
using f32x4   = __attribute__((ext_vector_type(4))) float;

__device__ __forceinline__ float lrelu(float x){ return x > 0.f ? x : NEG*x; }
__device__ __forceinline__ unsigned short f2bf(float f){
  unsigned u = __float_as_uint(f);
  u += 0x7fffu + ((u >> 16) & 1u);
  return (unsigned short)(u >> 16);
}
__device__ __forceinline__ float bf2f(unsigned short h){
  return __uint_as_float(((unsigned)h) << 16);
}

// ---------- prep ----------
__global__ void cast_x_kernel(const float* __restrict__ x, unsigned short* __restrict__ xb){
  int i = blockIdx.x*blockDim.x + threadIdx.x;
  int base = i*4;
  if (base >= N_NODES*F_IN) return;
  float4 v = *(const float4*)(x + base);
  ushort4 o; o.x=f2bf(v.x); o.y=f2bf(v.y); o.z=f2bf(v.z); o.w=f2bf(v.w);
  *(ushort4*)(xb + base) = o;
}
// W[K][Nc] fp32 -> Wt[Nc][K] bf16
__global__ void transpose_w_kernel(const float* __restrict__ W, unsigned short* __restrict__ Wt,
                                   int K, int Nc){
  int i = blockIdx.x*blockDim.x + threadIdx.x;
  if (i >= K*Nc) return;
  int n = i / K, k = i % K;
  Wt[i] = f2bf(W[(size_t)k*Nc + n]);
}
// wAb[c][k] bf16, c<12: W1·att_src (head c); 12<=c<24: W1·att_dst; else 0
__global__ void wab_prep(const float* __restrict__ W1, const float* __restrict__ att_src,
                         const float* __restrict__ att_dst, unsigned short* __restrict__ wAb){
  int i = blockIdx.x*blockDim.x + threadIdx.x;
  if (i >= 32*F_IN) return;
  int c = i >> 7, k = i & 127;
  float v = 0.f;
  if (c < 12){
    #pragma unroll
    for (int dd=0; dd<D1; ++dd) v += W1[(size_t)k*C1 + c*D1 + dd] * att_src[c*D1 + dd];
  } else if (c < 24){
    int h = c - 12;
    #pragma unroll
    for (int dd=0; dd<D1; ++dd) v += W1[(size_t)k*C1 + h*D1 + dd] * att_dst[h*D1 + dd];
  }
  wAb[i] = f2bf(v);
}

// ---------- bf16 MFMA GEMM: C[M][N] = A[M][K] @ Bt[N][K]^T ----------
template<int BM,int BN,int WM,int WN,bool F32OUT>
__global__ __launch_bounds__(256) void gemm_mfma(const unsigned short* __restrict__ A,
    const unsigned short* __restrict__ Bt, void* __restrict__ Cv,
    int M, int N, int K){
  constexpr int BK = 32;
  __shared__ unsigned short As2[4][BM][8];
  __shared__ unsigned short Bs2[4][BN][8];
  const int tid  = threadIdx.x;
  const int wid  = tid >> 6, lane = tid & 63;
  constexpr int NWX = BN / WN;
  const int wrow = (wid / NWX) * WM, wcol = (wid % NWX) * WN;
  constexpr int MR = WM/16, NR = WN/16;
  const int row0 = blockIdx.x * BM, col0 = blockIdx.y * BN;
  const int r = lane & 15, koct = lane >> 4;
  f32x4 acc[MR][NR];
  #pragma unroll
  for (int m=0;m<MR;m++)
    #pragma unroll
    for (int n=0;n<NR;n++) acc[m][n] = f32x4{0.f,0.f,0.f,0.f};

  for (int k0 = 0; k0 < K; k0 += BK){
    for (int s = tid; s < BM*8; s += 256){
      int rr = s >> 3, cc = (s & 7) * 4;
      int gr = row0 + rr;
      ushort4 v = (gr < M) ? *(const ushort4*)(A + (size_t)gr*K + k0 + cc)
                           : ushort4{0,0,0,0};
      *(ushort4*)(&As2[cc>>3][rr][cc&7]) = v;
    }
    for (int s = tid; s < BN*8; s += 256){
      int rr = s >> 3, cc = (s & 7) * 4;
      ushort4 v = *(const ushort4*)(Bt + (size_t)(col0+rr)*K + k0 + cc);
      *(ushort4*)(&Bs2[cc>>3][rr][cc&7]) = v;
    }
    __syncthreads();
    bf16x8 af[MR], bq[NR];
    #pragma unroll
    for (int m=0;m<MR;m++) af[m] = *(const bf16x8*)(&As2[koct][wrow + m*16 + r][0]);
    #pragma unroll
    for (int n=0;n<NR;n++) bq[n] = *(const bf16x8*)(&Bs2[koct][wcol + n*16 + r][0]);
    #pragma unroll
    for (int m=0;m<MR;m++)
      #pragma unroll
      for (int n=0;n<NR;n++)
        acc[m][n] = __builtin_amdgcn_mfma_f32_16x16x32_bf16(af[m], bq[n], acc[m][n], 0,0,0);
    __syncthreads();
  }
  #pragma unroll
  for (int m=0;m<MR;m++){
    #pragma unroll
    for (int rr=0; rr<4; rr++){
      int grow = row0 + wrow + m*16 + koct*4 + rr;
      if (grow < M){
        #pragma unroll
        for (int n=0;n<NR;n++){
          if constexpr (F32OUT)
            ((float*)Cv)[(size_t)grow*N + col0 + wcol + n*16 + r] = acc[m][n][rr];
          else
            ((unsigned short*)Cv)[(size_t)grow*N + col0 + wcol + n*16 + r] = f2bf(acc[m][n][rr]);
        }
      }
    }
  }
}

// ---------- CSR build ----------
__global__ void count_kernel(const int* __restrict__ ei, int* __restrict__ counts){
  int e = blockIdx.x*blockDim.x + threadIdx.x;
  if (e >= ETOT) return;
  int d = (e < N_EDGES) ? ei[N_EDGES + e] : (e - N_EDGES);
  atomicAdd(&counts[d], 1);
}
__global__ __launch_bounds__(SCAN_B) void scan_pass1(const int* __restrict__ counts,
    int* __restrict__ excl, int* __restrict__ bsum){
  __shared__ int sdata[SCAN_B];
  int i = blockIdx.x*SCAN_B + threadIdx.x;
  int v = (i < N_NODES) ? counts[i] : 0;
  sdata[threadIdx.x] = v;
  __syncthreads();
  for (int off=1; off<SCAN_B; off<<=1){
    int t = (threadIdx.x >= off) ? sdata[threadIdx.x-off] : 0;
    __syncthreads();
    sdata[threadIdx.x] += t;
    __syncthreads();
  }
  if (i < N_NODES) excl[i] = sdata[threadIdx.x] - v;
  if (threadIdx.x == SCAN_B-1) bsum[blockIdx.x] = sdata[SCAN_B-1];
}
__global__ void scan_pass2(int* __restrict__ bsum){
  if (threadIdx.x == 0){
    int acc = 0;
    for (int b=0;b<NBLK_SCAN;b++){ int t = bsum[b]; bsum[b] = acc; acc += t; }
  }
}
__global__ void scan_pass3(int* __restrict__ rowptr, const int* __restrict__ bsum,
                           int* __restrict__ cursor){
  int i = blockIdx.x*blockDim.x + threadIdx.x;
  if (i < N_NODES){
    int r = rowptr[i] + bsum[i/SCAN_B];
    rowptr[i] = r; cursor[i] = r;
  }
  if (i == N_NODES) rowptr[N_NODES] = ETOT;
}
__global__ void scatter_kernel(const int* __restrict__ ei, int* __restrict__ cursor,
                               int* __restrict__ csr_src){
  int e = blockIdx.x*blockDim.x + threadIdx.x;
  if (e >= ETOT) return;
  int s, d;
  if (e < N_EDGES){ s = ei[e]; d = ei[N_EDGES + e]; } else { s = d = e - N_EDGES; }
  int slot = atomicAdd(&cursor[d], 1);
  csr_src[slot] = s;
}

// ---------- conv1 fused: softmax + x-space aggregation + per-head MFMA transform ----------
// 512 threads = 8 waves; wave handles 2 dst (32 lanes each, 2-edge ILP);
// weights staged per-16-edge chunk in LDS; epilogue MFMA over 16 dst rows.
__global__ __launch_bounds__(512) void agg1f_kernel(const int* __restrict__ rowptr,
    const int* __restrict__ csr, const unsigned short* __restrict__ xb,
    const float* __restrict__ asd, const unsigned short* __restrict__ w1t,
    const float* __restrict__ bias, unsigned short* __restrict__ out1){
  constexpr int ROWE = 6*F_IN + 8;            // 776 ushorts
  __shared__ unsigned short agg[16*ROWE];     // 24832 B
  __shared__ float wlds[16][16*12];           // 12288 B
  __shared__ int   slds[16][16];              // 1024 B

  const int tid  = threadIdx.x;
  const int wv   = tid >> 6;        // 0..7
  const int lane = tid & 63;
  const int half = lane >> 5;       // which dst of the wave's pair
  const int t    = lane & 31;       // lane within dst
  const int eh   = t >> 4;          // edge parity (2-edge ILP)
  const int t16  = t & 15;          // feature chunk (8 bf16 each)
  const int slot = wv*2 + half;     // 0..15 dst slot in block
  const int d    = blockIdx.x*16 + slot;
  const int r0 = rowptr[d], r1 = rowptr[d+1];

  // dst attention halves (broadcast loads)
  float4 ad0 = *(const float4*)(asd + (size_t)d*32 + 12);
  float4 ad1 = *(const float4*)(asd + (size_t)d*32 + 16);
  float4 ad2 = *(const float4*)(asd + (size_t)d*32 + 20);
  float ad[12] = {ad0.x,ad0.y,ad0.z,ad0.w, ad1.x,ad1.y,ad1.z,ad1.w, ad2.x,ad2.y,ad2.z,ad2.w};

  // ---- pass A: per-head max over incoming edges (32-lane strided) ----
  float mx[12];
  #pragma unroll
  for (int h=0;h<12;h++) mx[h] = -1e30f;
  for (int j = r0 + t; j < r1; j += 32){
    int s = csr[j];
    float4 s0 = *(const float4*)(asd + (size_t)s*32);
    float4 s1 = *(const float4*)(asd + (size_t)s*32 + 4);
    float4 s2 = *(const float4*)(asd + (size_t)s*32 + 8);
    float as[12] = {s0.x,s0.y,s0.z,s0.w, s1.x,s1.y,s1.z,s1.w, s2.x,s2.y,s2.z,s2.w};
    #pragma unroll
    for (int h=0;h<12;h++) mx[h] = fmaxf(mx[h], lrelu(as[h] + ad[h]));
  }
  #pragma unroll
  for (int h=0;h<12;h++){
    #pragma unroll
    for (int off=16; off; off>>=1) mx[h] = fmaxf(mx[h], __shfl_xor(mx[h], off));
  }

  // ---- pass B: chunked stage (unnormalized w) + aggregate ----
  float acc[12][8];
  #pragma unroll
  for (int h=0;h<12;h++)
    #pragma unroll
    for (int i=0;i<8;i++) acc[h][i] = 0.f;
  float ssp[12];
  #pragma unroll
  for (int h=0;h<12;h++) ssp[h] = 0.f;

  for (int c0 = r0; c0 < r1; c0 += 16){
    int nc = min(16, r1 - c0);
    if (t < nc){
      int s = csr[c0 + t];
      slds[slot][t] = s;
      float4 s0 = *(const float4*)(asd + (size_t)s*32);
      float4 s1 = *(const float4*)(asd + (size_t)s*32 + 4);
      float4 s2 = *(const float4*)(asd + (size_t)s*32 + 8);
      float as[12] = {s0.x,s0.y,s0.z,s0.w, s1.x,s1.y,s1.z,s1.w, s2.x,s2.y,s2.z,s2.w};
      float w[12];
      #pragma unroll
      for (int h=0;h<12;h++){ w[h] = __expf(lrelu(as[h] + ad[h]) - mx[h]); ssp[h] += w[h]; }
      *(float4*)(&wlds[slot][t*12 + 0]) = float4{w[0],w[1],w[2],w[3]};
      *(float4*)(&wlds[slot][t*12 + 4]) = float4{w[4],w[5],w[6],w[7]};
      *(float4*)(&wlds[slot][t*12 + 8]) = float4{w[8],w[9],w[10],w[11]};
    }
    __builtin_amdgcn_wave_barrier();   // wave-synchronous LDS: keep compiler order
    for (int e0 = 0; e0 < nc; e0 += 2){
      int e = e0 + eh;
      bool valid = e < nc;
      int ee = valid ? e : 0;
      int s = slds[slot][ee];
      float4 w0 = *(const float4*)(&wlds[slot][ee*12 + 0]);
      float4 w1 = *(const float4*)(&wlds[slot][ee*12 + 4]);
      float4 w2 = *(const float4*)(&wlds[slot][ee*12 + 8]);
      if (!valid){ w0 = float4{0,0,0,0}; w1 = float4{0,0,0,0}; w2 = float4{0,0,0,0}; }
      ushort8 cx = *(const ushort8*)(xb + (size_t)s*F_IN + t16*8);
      float xf[8];
      #pragma unroll
      for (int i=0;i<8;i++) xf[i] = bf2f((unsigned short)cx[i]);
      float w[12] = {w0.x,w0.y,w0.z,w0.w, w1.x,w1.y,w1.z,w1.w, w2.x,w2.y,w2.z,w2.w};
      #pragma unroll
      for (int h=0;h<12;h++)
        #pragma unroll
        for (int i=0;i<8;i++) acc[h][i] += w[h]*xf[i];
    }
    __builtin_amdgcn_wave_barrier();   // agg reads done before next chunk's stage overwrites
  }

  // ---- finalize: reduce ss over lanes, reduce acc over edge parity, normalize ----
  #pragma unroll
  for (int h=0;h<12;h++){
    #pragma unroll
    for (int off=16; off; off>>=1) ssp[h] += __shfl_xor(ssp[h], off);
  }
  #pragma unroll
  for (int h=0;h<12;h++)
    #pragma unroll
    for (int i=0;i<8;i++) acc[h][i] += __shfl_xor(acc[h][i], 16);
  float inv[12];
  #pragma unroll
  for (int h=0;h<12;h++) inv[h] = 1.f / ssp[h];

  // ---- epilogue: agg(bf16, LDS) @ W1 per head, two halves of 6 heads ----
  const int er = lane & 15, eq = lane >> 4;   // MFMA row / k-oct
  #pragma unroll
  for (int hf = 0; hf < 2; ++hf){
    __syncthreads();   // all waves here; prev half's MFMA reads complete
    if (eh == 0){
      #pragma unroll
      for (int h = 0; h < 6; ++h){
        int hh = hf*6 + h;
        ushort8 v;
        #pragma unroll
        for (int i=0;i<8;i++) v[i] = f2bf(acc[hh][i]*inv[hh]);
        *(ushort8*)(&agg[slot*ROWE + h*F_IN + t16*8]) = v;
      }
    }
    __syncthreads();
    for (int tt = wv; tt < 12; tt += 8){
      int h = tt >> 1, nb = tt & 1;
      int hh = hf*6 + h;
      f32x4 c = {0.f,0.f,0.f,0.f};
      #pragma unroll
      for (int kk=0; kk<4; ++kk){
        bf16x8 af = *(const bf16x8*)(&agg[er*ROWE + h*F_IN + kk*32 + eq*8]);
        bf16x8 bq = *(const bf16x8*)(w1t + (size_t)(hh*32 + nb*16 + er)*F_IN + kk*32 + eq*8);
        c = __builtin_amdgcn_mfma_f32_16x16x32_bf16(af, bq, c, 0,0,0);
      }
      int col = hh*32 + nb*16 + er;
      float bv = bias[col];
      #pragma unroll
      for (int rr=0; rr<4; ++rr){
        int od = blockIdx.x*16 + eq*4 + rr;
        out1[(size_t)od*C1 + col] = f2bf(fmaxf(c[rr] + bv, 0.f));
      }
    }
  }
}

// ---------- per-node attention halves, conv2 ----------
__global__ void a2_kernel(const unsigned short* __restrict__ h2,
    const float* __restrict__ att_src, const float* __restrict__ att_dst,
    float* __restrict__ a_src, float* __restrict__ a_dst){
  int n = blockIdx.x*blockDim.x + threadIdx.x;
  if (n >= N_NODES) return;
  const unsigned short* hp = h2 + (size_t)n*C2;
  float s=0.f, d=0.f;
  #pragma unroll
  for (int k4=0;k4<16;k4++){
    ushort4 v = *(const ushort4*)(hp + k4*4);
    int b = k4*4;
    s += bf2f(v.x)*att_src[b] + bf2f(v.y)*att_src[b+1] + bf2f(v.z)*att_src[b+2] + bf2f(v.w)*att_src[b+3];
    d += bf2f(v.x)*att_dst[b] + bf2f(v.y)*att_dst[b+1] + bf2f(v.z)*att_dst[b+2] + bf2f(v.w)*att_dst[b+3];
  }
  a_src[n]=s; a_dst[n]=d;
}

// ---------- conv2: fused softmax + aggregation + mean-pool atomics ----------
#define AGG2_CH 64
__global__ __launch_bounds__(64) void agg2f_kernel(const int* __restrict__ rowptr,
    const int* __restrict__ csr, const unsigned short* __restrict__ h2,
    const float* __restrict__ asrc, const float* __restrict__ adst,
    const float* __restrict__ bias, const int* __restrict__ batch,
    float* __restrict__ pool){
  int d = blockIdx.x, tid = threadIdx.x;
  int r0 = rowptr[d], r1 = rowptr[d+1];
  float ad = adst[d];
  float m = -1e30f, ss = 0.f;
  for (int j = r0 + tid; j < r1; j += 64){
    float l = lrelu(asrc[csr[j]] + ad);
    float mn = fmaxf(m, l);
    ss = ss*__expf(m - mn) + __expf(l - mn);
    m = mn;
  }
  #pragma unroll
  for (int off=32; off; off>>=1){
    float m2 = __shfl_xor(m, off);
    float s2 = __shfl_xor(ss, off);
    float mn = fmaxf(m, m2);
    ss = ss*__expf(m - mn) + s2*__expf(m2 - mn);
    m = mn;
  }
  float inv = 1.f / ss;
  __shared__ int   s_lds[AGG2_CH];
  __shared__ float red[3][C2];
  int grp = tid >> 4;
  int fb  = (tid & 15) * 4;
  float a0=0.f, a1=0.f, a2=0.f, a3=0.f;
  for (int c0 = r0; c0 < r1; c0 += AGG2_CH){
    int nc = min(AGG2_CH, r1 - c0);
    __syncthreads();
    if (tid < nc) s_lds[tid] = csr[c0 + tid];
    __syncthreads();
    for (int e = grp; e < nc; e += 4){
      int s = s_lds[e];
      float w = __expf(lrelu(asrc[s] + ad) - m);
      ushort4 hv = *(const ushort4*)(h2 + (size_t)s*C2 + fb);
      a0 += w*bf2f(hv.x); a1 += w*bf2f(hv.y); a2 += w*bf2f(hv.z); a3 += w*bf2f(hv.w);
    }
  }
  __syncthreads();
  if (grp > 0){
    float* p = &red[grp-1][fb];
    p[0]=a0; p[1]=a1; p[2]=a2; p[3]=a3;
  }
  __syncthreads();
  if (grp == 0){
    int g = batch[d];
    float4 b4 = *(const float4*)(bias + fb);
    float v0 = (a0 + red[0][fb+0] + red[1][fb+0] + red[2][fb+0])*inv + b4.x;
    float v1 = (a1 + red[0][fb+1] + red[1][fb+1] + red[2][fb+1])*inv + b4.y;
    float v2 = (a2 + red[0][fb+2] + red[1][fb+2] + red[2][fb+2])*inv + b4.z;
    float v3 = (a3 + red[0][fb+3] + red[1][fb+3] + red[2][fb+3])*inv + b4.w;
    atomicAdd(&pool[g*C2 + fb+0], v0);
    atomicAdd(&pool[g*C2 + fb+1], v1);
    atomicAdd(&pool[g*C2 + fb+2], v2);
    atomicAdd(&pool[g*C2 + fb+3], v3);
  }
}

__global__ void cnt_kernel(const int* __restrict__ batch, int* __restrict__ cnt){
  int n = blockIdx.x*blockDim.x + threadIdx.x;
  if (n < N_NODES) atomicAdd(&cnt[batch[n]], 1);
}
__global__ void finalize_kernel(const float* __restrict__ sums, const int* __restrict__ cnt,
                                float* __restrict__ out){
  int i = blockIdx.x*blockDim.x + threadIdx.x;
  if (i >= G_GRAPHS*C2) return;
  int g = i >> 6;
  out[i] = sums[i] / fmaxf((float)cnt[g], 1.f);
}

// ---------- launch ----------
extern "C" void kernel_launch(void* const* d_in, const int* in_sizes, int n_in,
                              void* d_out, int out_size, void* d_ws, size_t ws_size,
                              hipStream_t stream) {
  const float* x        = (const float*)d_in[0];
  const int*   ei       = (const int*)  d_in[1];
  const int*   batch    = (const int*)  d_in[2];
  const float* W1       = (const float*)d_in[3];
  const float* att_src1 = (const float*)d_in[4];
  const float* att_dst1 = (const float*)d_in[5];
  const float* bias1    = (const float*)d_in[6];
  const float* W2       = (const float*)d_in[7];
  const float* att_src2 = (const float*)d_in[8];
  const float* att_dst2 = (const float*)d_in[9];
  const float* bias2    = (const float*)d_in[10];
  float* out = (float*)d_out;

  char* ws = (char*)d_ws;
  size_t o = 0;
  auto alloc = [&](size_t bytes)->size_t{ size_t r=o; o=(o+bytes+255)&~(size_t)255; return r; };

  size_t xb_o     = alloc((size_t)N_NODES*F_IN*2);   // 12.8 MB
  size_t w1t_o    = alloc((size_t)C1*F_IN*2);
  size_t w2t_o    = alloc((size_t)C2*C1*2);
  size_t wab_o    = alloc((size_t)32*F_IN*2);
  size_t asd_o    = alloc((size_t)N_NODES*32*4);     // 6.4 MB (src:0-11, dst:12-23)
  size_t out1_o   = alloc((size_t)N_NODES*C1*2);     // 38.4 MB
  size_t h2_o     = alloc((size_t)N_NODES*C2*2);     // 6.4 MB
  size_t asrc2_o  = alloc((size_t)N_NODES*4);
  size_t adst2_o  = alloc((size_t)N_NODES*4);
  size_t zero_beg = o;
  size_t counts_o = alloc((size_t)N_NODES*4);
  size_t pool_o   = alloc((size_t)G_GRAPHS*C2*4);
  size_t cnt_o    = alloc((size_t)G_GRAPHS*4);
  size_t zero_end = o;
  size_t rowptr_o = alloc((size_t)(N_NODES+1)*4);
  size_t bsum_o   = alloc((size_t)NBLK_SCAN*4);
  size_t cursor_o = alloc((size_t)N_NODES*4);
  size_t csr_o    = alloc((size_t)ETOT*4);

  unsigned short* xb    = (unsigned short*)(ws + xb_o);
  unsigned short* w1t   = (unsigned short*)(ws + w1t_o);
  unsigned short* w2t   = (unsigned short*)(ws + w2t_o);
  unsigned short* wab   = (unsigned short*)(ws + wab_o);
  float* asd    = (float*)(ws + asd_o);
  unsigned short* out1b = (unsigned short*)(ws + out1_o);
  unsigned short* h2b   = (unsigned short*)(ws + h2_o);
  float* asrc2  = (float*)(ws + asrc2_o);
  float* adst2  = (float*)(ws + adst2_o);
  int*   counts = (int*)  (ws + counts_o);
  float* poolf  = (float*)(ws + pool_o);
  int*   cnt    = (int*)  (ws + cnt_o);
  int*   rowptr = (int*)  (ws + rowptr_o);
  int*   bsum   = (int*)  (ws + bsum_o);
  int*   cursor = (int*)  (ws + cursor_o);
  int*   csrsrc = (int*)  (ws + csr_o);

  hipMemsetAsync(ws + zero_beg, 0, zero_end - zero_beg, stream);

  const int TPB = 256;
  int egrid = (ETOT + TPB - 1)/TPB;

  // prep
  cast_x_kernel<<<(N_NODES*F_IN/4 + TPB-1)/TPB, TPB, 0, stream>>>(x, xb);
  transpose_w_kernel<<<(F_IN*C1 + TPB-1)/TPB, TPB, 0, stream>>>(W1, w1t, F_IN, C1);
  transpose_w_kernel<<<(C1*C2 + TPB-1)/TPB, TPB, 0, stream>>>(W2, w2t, C1, C2);
  wab_prep<<<(32*F_IN + TPB-1)/TPB, TPB, 0, stream>>>(W1, att_src1, att_dst1, wab);

  // CSR build
  count_kernel<<<egrid, TPB, 0, stream>>>(ei, counts);
  scan_pass1<<<NBLK_SCAN, SCAN_B, 0, stream>>>(counts, rowptr, bsum);
  scan_pass2<<<1, 64, 0, stream>>>(bsum);
  scan_pass3<<<(N_NODES + TPB)/TPB, TPB, 0, stream>>>(rowptr, bsum, cursor);
  scatter_kernel<<<egrid, TPB, 0, stream>>>(ei, cursor, csrsrc);

  // conv1: logits GEMM -> fused softmax+agg+transform
  gemm_mfma<128,32,32,32,true><<<dim3((N_NODES+127)/128, 1), 256, 0, stream>>>(xb, wab, asd, N_NODES, 32, F_IN);
  agg1f_kernel<<<N_NODES/16, 512, 0, stream>>>(rowptr, csrsrc, xb, asd, w1t, bias1, out1b);

  // conv2
  gemm_mfma<128,64,64,32,false><<<dim3((N_NODES+127)/128, 1), 256, 0, stream>>>(out1b, w2t, h2b, N_NODES, C2, C1);
  a2_kernel<<<(N_NODES + TPB-1)/TPB, TPB, 0, stream>>>(h2b, att_src2, att_dst2, asrc2, adst2);
  agg2f_kernel<<<N_NODES, 64, 0, stream>>>(rowptr, csrsrc, h2b, asrc2, adst2, bias2, batch, poolf);

  // pool finalize
  cnt_kernel<<<(N_NODES + TPB-1)/TPB, TPB, 0, stream>>>(batch, cnt);
  finalize_kernel<<<(G_GRAPHS*C2 + TPB-1)/TPB, TPB, 0, stream>>>(poolf, cnt, out);
}

// Round 7
// 530.477 us; speedup vs baseline: 1.0020x; 1.0020x over previous
//
#include <hip/hip_runtime.h>

#define N_NODES 50000
#define N_EDGES 800000
#define ETOT (N_EDGES + N_NODES)   // 850000
#define G_GRAPHS 256
#define F_IN 128
#define H1 12
#define D1 32
#define C1 (H1*D1)   // 384
#define C2 64
#define NEG 0.2f
#define SCAN_B 1024
#define NBLK_SCAN ((N_NODES + SCAN_B - 1)/SCAN_B)   // 49

using bf16x8  = __attribute__((ext_vector_type(8))) short;
using ushort8 = __attribute__((ext_vector_type(8))) unsigned short;
using f32x4   = __attribute__((ext_vector_type(4))) float;

__device__ __forceinline__ float lrelu(float x){ return x > 0.f ? x : NEG*x; }
__device__ __forceinline__ unsigned short f2bf(float f){
  unsigned u = __float_as_uint(f);
  u += 0x7fffu + ((u >> 16) & 1u);
  return (unsigned short)(u >> 16);
}
__device__ __forceinline__ float bf2f(unsigned short h){
  return __uint_as_float(((unsigned)h) << 16);
}

// ---------- prep ----------
__global__ void cast_x_kernel(const float* __restrict__ x, unsigned short* __restrict__ xb){
  int i = blockIdx.x*blockDim.x + threadIdx.x;
  int base = i*4;
  if (base >= N_NODES*F_IN) return;
  float4 v = *(const float4*)(x + base);
  ushort4 o; o.x=f2bf(v.x); o.y=f2bf(v.y); o.z=f2bf(v.z); o.w=f2bf(v.w);
  *(ushort4*)(xb + base) = o;
}
// W[K][Nc] fp32 -> Wt[Nc][K] bf16
__global__ void transpose_w_kernel(const float* __restrict__ W, unsigned short* __restrict__ Wt,
                                   int K, int Nc){
  int i = blockIdx.x*blockDim.x + threadIdx.x;
  if (i >= K*Nc) return;
  int n = i / K, k = i % K;
  Wt[i] = f2bf(W[(size_t)k*Nc + n]);
}
// wAb[c][k] bf16, c<12: W1·att_src (head c); 12<=c<24: W1·att_dst; else 0
__global__ void wab_prep(const float* __restrict__ W1, const float* __restrict__ att_src,
                         const float* __restrict__ att_dst, unsigned short* __restrict__ wAb){
  int i = blockIdx.x*blockDim.x + threadIdx.x;
  if (i >= 32*F_IN) return;
  int c = i >> 7, k = i & 127;
  float v = 0.f;
  if (c < 12){
    #pragma unroll
    for (int dd=0; dd<D1; ++dd) v += W1[(size_t)k*C1 + c*D1 + dd] * att_src[c*D1 + dd];
  } else if (c < 24){
    int h = c - 12;
    #pragma unroll
    for (int dd=0; dd<D1; ++dd) v += W1[(size_t)k*C1 + h*D1 + dd] * att_dst[h*D1 + dd];
  }
  wAb[i] = f2bf(v);
}

// ---------- bf16 MFMA GEMM: C[M][N] = A[M][K] @ Bt[N][K]^T ----------
template<int BM,int BN,int WM,int WN,bool F32OUT>
__global__ __launch_bounds__(256) void gemm_mfma(const unsigned short* __restrict__ A,
    const unsigned short* __restrict__ Bt, void* __restrict__ Cv,
    int M, int N, int K){
  constexpr int BK = 32;
  __shared__ unsigned short As2[4][BM][8];
  __shared__ unsigned short Bs2[4][BN][8];
  const int tid  = threadIdx.x;
  const int wid  = tid >> 6, lane = tid & 63;
  constexpr int NWX = BN / WN;
  const int wrow = (wid / NWX) * WM, wcol = (wid % NWX) * WN;
  constexpr int MR = WM/16, NR = WN/16;
  const int row0 = blockIdx.x * BM, col0 = blockIdx.y * BN;
  const int r = lane & 15, koct = lane >> 4;
  f32x4 acc[MR][NR];
  #pragma unroll
  for (int m=0;m<MR;m++)
    #pragma unroll
    for (int n=0;n<NR;n++) acc[m][n] = f32x4{0.f,0.f,0.f,0.f};

  for (int k0 = 0; k0 < K; k0 += BK){
    for (int s = tid; s < BM*8; s += 256){
      int rr = s >> 3, cc = (s & 7) * 4;
      int gr = row0 + rr;
      ushort4 v = (gr < M) ? *(const ushort4*)(A + (size_t)gr*K + k0 + cc)
                           : ushort4{0,0,0,0};
      *(ushort4*)(&As2[cc>>3][rr][cc&7]) = v;
    }
    for (int s = tid; s < BN*8; s += 256){
      int rr = s >> 3, cc = (s & 7) * 4;
      ushort4 v = *(const ushort4*)(Bt + (size_t)(col0+rr)*K + k0 + cc);
      *(ushort4*)(&Bs2[cc>>3][rr][cc&7]) = v;
    }
    __syncthreads();
    bf16x8 af[MR], bq[NR];
    #pragma unroll
    for (int m=0;m<MR;m++) af[m] = *(const bf16x8*)(&As2[koct][wrow + m*16 + r][0]);
    #pragma unroll
    for (int n=0;n<NR;n++) bq[n] = *(const bf16x8*)(&Bs2[koct][wcol + n*16 + r][0]);
    #pragma unroll
    for (int m=0;m<MR;m++)
      #pragma unroll
      for (int n=0;n<NR;n++)
        acc[m][n] = __builtin_amdgcn_mfma_f32_16x16x32_bf16(af[m], bq[n], acc[m][n], 0,0,0);
    __syncthreads();
  }
  #pragma unroll
  for (int m=0;m<MR;m++){
    #pragma unroll
    for (int rr=0; rr<4; rr++){
      int grow = row0 + wrow + m*16 + koct*4 + rr;
      if (grow < M){
        #pragma unroll
        for (int n=0;n<NR;n++){
          if constexpr (F32OUT)
            ((float*)Cv)[(size_t)grow*N + col0 + wcol + n*16 + r] = acc[m][n][rr];
          else
            ((unsigned short*)Cv)[(size_t)grow*N + col0 + wcol + n*16 + r] = f2bf(acc[m][n][rr]);
        }
      }
    }
  }
}

// ---------- CSR build ----------
__global__ void count_kernel(const int* __restrict__ ei, int* __restrict__ counts){
  int e = blockIdx.x*blockDim.x + threadIdx.x;
  if (e >= ETOT) return;
  int d = (e < N_EDGES) ? ei[N_EDGES + e] : (e - N_EDGES);
  atomicAdd(&counts[d], 1);
}
__global__ __launch_bounds__(SCAN_B) void scan_pass1(const int* __restrict__ counts,
    int* __restrict__ excl, int* __restrict__ bsum){
  __shared__ int sdata[SCAN_B];
  int i = blockIdx.x*SCAN_B + threadIdx.x;
  int v = (i < N_NODES) ? counts[i] : 0;
  sdata[threadIdx.x] = v;
  __syncthreads();
  for (int off=1; off<SCAN_B; off<<=1){
    int t = (threadIdx.x >= off) ? sdata[threadIdx.x-off] : 0;
    __syncthreads();
    sdata[threadIdx.x] += t;
    __syncthreads();
  }
  if (i < N_NODES) excl[i] = sdata[threadIdx.x] - v;
  if (threadIdx.x == SCAN_B-1) bsum[blockIdx.x] = sdata[SCAN_B-1];
}
__global__ void scan_pass2(int* __restrict__ bsum){
  if (threadIdx.x == 0){
    int acc = 0;
    for (int b=0;b<NBLK_SCAN;b++){ int t = bsum[b]; bsum[b] = acc; acc += t; }
  }
}
__global__ void scan_pass3(int* __restrict__ rowptr, const int* __restrict__ bsum,
                           int* __restrict__ cursor){
  int i = blockIdx.x*blockDim.x + threadIdx.x;
  if (i < N_NODES){
    int r = rowptr[i] + bsum[i/SCAN_B];
    rowptr[i] = r; cursor[i] = r;
  }
  if (i == N_NODES) rowptr[N_NODES] = ETOT;
}
__global__ void scatter_kernel(const int* __restrict__ ei, int* __restrict__ cursor,
                               int* __restrict__ csr_src){
  int e = blockIdx.x*blockDim.x + threadIdx.x;
  if (e >= ETOT) return;
  int s, d;
  if (e < N_EDGES){ s = ei[e]; d = ei[N_EDGES + e]; } else { s = d = e - N_EDGES; }
  int slot = atomicAdd(&cursor[d], 1);
  csr_src[slot] = s;
}

// ---------- alpha (conv1, 12 heads): 1 wave per dst, 4 dst/block ----------
__global__ __launch_bounds__(256) void alpha1_kernel(const int* __restrict__ rowptr,
    const int* __restrict__ csr, const float* __restrict__ asd,
    float* __restrict__ alpha){
  int d = blockIdx.x*4 + (threadIdx.x >> 6);
  int lane = threadIdx.x & 63;
  int r0 = rowptr[d], r1 = rowptr[d+1], deg = r1 - r0;
  float4 ad0 = *(const float4*)(asd + (size_t)d*32 + 12);
  float4 ad1 = *(const float4*)(asd + (size_t)d*32 + 16);
  float4 ad2 = *(const float4*)(asd + (size_t)d*32 + 20);
  float ad[12] = {ad0.x,ad0.y,ad0.z,ad0.w, ad1.x,ad1.y,ad1.z,ad1.w, ad2.x,ad2.y,ad2.z,ad2.w};

  if (deg <= 64){
    bool act = lane < deg;
    int j = r0 + lane;
    int s = act ? csr[j] : 0;
    float4 s0 = *(const float4*)(asd + (size_t)s*32);
    float4 s1 = *(const float4*)(asd + (size_t)s*32 + 4);
    float4 s2 = *(const float4*)(asd + (size_t)s*32 + 8);
    float as[12] = {s0.x,s0.y,s0.z,s0.w, s1.x,s1.y,s1.z,s1.w, s2.x,s2.y,s2.z,s2.w};
    float w[12];
    #pragma unroll
    for (int h=0; h<12; ++h){
      float l = act ? lrelu(as[h] + ad[h]) : -1e30f;
      float m = l;
      #pragma unroll
      for (int off=32; off; off>>=1) m = fmaxf(m, __shfl_xor(m, off));
      float wv = act ? __expf(l - m) : 0.f;
      float ss = wv;
      #pragma unroll
      for (int off=32; off; off>>=1) ss += __shfl_xor(ss, off);
      w[h] = wv / ss;
    }
    if (act){
      *(float4*)(alpha + (size_t)j*12)     = float4{w[0],w[1],w[2],w[3]};
      *(float4*)(alpha + (size_t)j*12 + 4) = float4{w[4],w[5],w[6],w[7]};
      *(float4*)(alpha + (size_t)j*12 + 8) = float4{w[8],w[9],w[10],w[11]};
    }
  } else {
    float mx[12], ss[12];
    #pragma unroll
    for (int h=0;h<12;h++){ mx[h] = -1e30f; ss[h] = 0.f; }
    for (int j = r0 + lane; j < r1; j += 64){
      int s = csr[j];
      float4 s0 = *(const float4*)(asd + (size_t)s*32);
      float4 s1 = *(const float4*)(asd + (size_t)s*32 + 4);
      float4 s2 = *(const float4*)(asd + (size_t)s*32 + 8);
      float as[12] = {s0.x,s0.y,s0.z,s0.w, s1.x,s1.y,s1.z,s1.w, s2.x,s2.y,s2.z,s2.w};
      #pragma unroll
      for (int h=0;h<12;h++) mx[h] = fmaxf(mx[h], lrelu(as[h] + ad[h]));
    }
    #pragma unroll
    for (int h=0;h<12;h++){
      #pragma unroll
      for (int off=32; off; off>>=1) mx[h] = fmaxf(mx[h], __shfl_xor(mx[h], off));
    }
    for (int j = r0 + lane; j < r1; j += 64){
      int s = csr[j];
      float4 s0 = *(const float4*)(asd + (size_t)s*32);
      float4 s1 = *(const float4*)(asd + (size_t)s*32 + 4);
      float4 s2 = *(const float4*)(asd + (size_t)s*32 + 8);
      float as[12] = {s0.x,s0.y,s0.z,s0.w, s1.x,s1.y,s1.z,s1.w, s2.x,s2.y,s2.z,s2.w};
      float w[12];
      #pragma unroll
      for (int h=0;h<12;h++){ w[h] = __expf(lrelu(as[h]+ad[h]) - mx[h]); ss[h] += w[h]; }
      *(float4*)(alpha + (size_t)j*12)     = float4{w[0],w[1],w[2],w[3]};
      *(float4*)(alpha + (size_t)j*12 + 4) = float4{w[4],w[5],w[6],w[7]};
      *(float4*)(alpha + (size_t)j*12 + 8) = float4{w[8],w[9],w[10],w[11]};
    }
    float inv[12];
    #pragma unroll
    for (int h=0;h<12;h++){
      #pragma unroll
      for (int off=32; off; off>>=1) ss[h] += __shfl_xor(ss[h], off);
      inv[h] = 1.f / ss[h];
    }
    for (int j = r0 + lane; j < r1; j += 64){
      float4 o0 = *(const float4*)(alpha + (size_t)j*12);
      float4 o1 = *(const float4*)(alpha + (size_t)j*12 + 4);
      float4 o2 = *(const float4*)(alpha + (size_t)j*12 + 8);
      o0.x*=inv[0]; o0.y*=inv[1]; o0.z*=inv[2]; o0.w*=inv[3];
      o1.x*=inv[4]; o1.y*=inv[5]; o1.z*=inv[6]; o1.w*=inv[7];
      o2.x*=inv[8]; o2.y*=inv[9]; o2.z*=inv[10]; o2.w*=inv[11];
      *(float4*)(alpha + (size_t)j*12)     = o0;
      *(float4*)(alpha + (size_t)j*12 + 4) = o1;
      *(float4*)(alpha + (size_t)j*12 + 8) = o2;
    }
  }
}

// ---------- conv1: x-space aggregation (32 lanes/dst, 4 feats/lane) + MFMA transform ----------
// 512 threads = 8 waves = 16 dst/block; acc[12][4] = 48 f32 regs/lane.
__global__ __launch_bounds__(512) void agg1x2_kernel(const int* __restrict__ rowptr,
    const int* __restrict__ csr, const unsigned short* __restrict__ xb,
    const float* __restrict__ alpha, const unsigned short* __restrict__ w1t,
    const float* __restrict__ bias, unsigned short* __restrict__ out1){
  constexpr int ROWE = 6*F_IN + 8;            // 776 ushorts
  __shared__ unsigned short agg[16*ROWE];     // 24832 B
  const int tid  = threadIdx.x;
  const int wv   = tid >> 6;        // 0..7
  const int lane = tid & 63;
  const int half = lane >> 5;       // dst of the wave's pair
  const int t    = lane & 31;       // feature chunk: feats [4t, 4t+4)
  const int slot = wv*2 + half;     // 0..15
  const int d    = blockIdx.x*16 + slot;
  const int r0 = rowptr[d], r1 = rowptr[d+1];

  float acc[12][4];
  #pragma unroll
  for (int h=0;h<12;h++)
    #pragma unroll
    for (int i=0;i<4;i++) acc[h][i] = 0.f;

  float4 a0={0,0,0,0}, a1={0,0,0,0}, a2={0,0,0,0};
  ushort4 xv = {0,0,0,0};
  if (r0 < r1){
    int s = csr[r0];
    a0 = *(const float4*)(alpha + (size_t)r0*12);
    a1 = *(const float4*)(alpha + (size_t)r0*12 + 4);
    a2 = *(const float4*)(alpha + (size_t)r0*12 + 8);
    xv = *(const ushort4*)(xb + (size_t)s*F_IN + t*4);
  }
  for (int j = r0; j < r1; ++j){
    float4 c0=a0, c1=a1, c2=a2; ushort4 cx=xv;
    if (j+1 < r1){
      int s = csr[j+1];
      a0 = *(const float4*)(alpha + (size_t)(j+1)*12);
      a1 = *(const float4*)(alpha + (size_t)(j+1)*12 + 4);
      a2 = *(const float4*)(alpha + (size_t)(j+1)*12 + 8);
      xv = *(const ushort4*)(xb + (size_t)s*F_IN + t*4);
    }
    float xf[4] = {bf2f(cx.x), bf2f(cx.y), bf2f(cx.z), bf2f(cx.w)};
    float w[12] = {c0.x,c0.y,c0.z,c0.w, c1.x,c1.y,c1.z,c1.w, c2.x,c2.y,c2.z,c2.w};
    #pragma unroll
    for (int h=0;h<12;h++)
      #pragma unroll
      for (int i=0;i<4;i++) acc[h][i] += w[h]*xf[i];
  }

  // ---- epilogue: agg(bf16, LDS) @ W1 per head, two halves of 6 heads ----
  const int er = lane & 15, eq = lane >> 4;   // MFMA row / k-oct
  #pragma unroll
  for (int hf = 0; hf < 2; ++hf){
    __syncthreads();   // prev half's MFMA reads complete before overwrite
    #pragma unroll
    for (int h = 0; h < 6; ++h){
      int hh = hf*6 + h;
      ushort4 v;
      v.x = f2bf(acc[hh][0]); v.y = f2bf(acc[hh][1]);
      v.z = f2bf(acc[hh][2]); v.w = f2bf(acc[hh][3]);
      *(ushort4*)(&agg[slot*ROWE + h*F_IN + t*4]) = v;
    }
    __syncthreads();
    for (int tt = wv; tt < 12; tt += 8){
      int h = tt >> 1, nb = tt & 1;
      int hh = hf*6 + h;
      f32x4 c = {0.f,0.f,0.f,0.f};
      #pragma unroll
      for (int kk=0; kk<4; ++kk){
        bf16x8 af = *(const bf16x8*)(&agg[er*ROWE + h*F_IN + kk*32 + eq*8]);
        bf16x8 bq = *(const bf16x8*)(w1t + (size_t)(hh*32 + nb*16 + er)*F_IN + kk*32 + eq*8);
        c = __builtin_amdgcn_mfma_f32_16x16x32_bf16(af, bq, c, 0,0,0);
      }
      int col = hh*32 + nb*16 + er;
      float bv = bias[col];
      #pragma unroll
      for (int rr=0; rr<4; ++rr){
        int od = blockIdx.x*16 + eq*4 + rr;
        out1[(size_t)od*C1 + col] = f2bf(fmaxf(c[rr] + bv, 0.f));
      }
    }
  }
}

// ---------- per-node attention halves, conv2 ----------
__global__ void a2_kernel(const unsigned short* __restrict__ h2,
    const float* __restrict__ att_src, const float* __restrict__ att_dst,
    float* __restrict__ a_src, float* __restrict__ a_dst){
  int n = blockIdx.x*blockDim.x + threadIdx.x;
  if (n >= N_NODES) return;
  const unsigned short* hp = h2 + (size_t)n*C2;
  float s=0.f, d=0.f;
  #pragma unroll
  for (int k4=0;k4<16;k4++){
    ushort4 v = *(const ushort4*)(hp + k4*4);
    int b = k4*4;
    s += bf2f(v.x)*att_src[b] + bf2f(v.y)*att_src[b+1] + bf2f(v.z)*att_src[b+2] + bf2f(v.w)*att_src[b+3];
    d += bf2f(v.x)*att_dst[b] + bf2f(v.y)*att_dst[b+1] + bf2f(v.z)*att_dst[b+2] + bf2f(v.w)*att_dst[b+3];
  }
  a_src[n]=s; a_dst[n]=d;
}

// ---------- conv2: single-pass online softmax + aggregation + pool atomics ----------
// 1 wave per dst (64 lanes = 64 feats), 4 dst per 256-thread block.
__global__ __launch_bounds__(256) void agg2o_kernel(const int* __restrict__ rowptr,
    const int* __restrict__ csr, const unsigned short* __restrict__ h2,
    const float* __restrict__ asrc, const float* __restrict__ adst,
    const float* __restrict__ bias, const int* __restrict__ batch,
    float* __restrict__ pool){
  int d = blockIdx.x*4 + (threadIdx.x >> 6);
  int lane = threadIdx.x & 63;
  int r0 = rowptr[d], r1 = rowptr[d+1];
  float ad = adst[d];
  float m = -1e30f, ss = 0.f, acc = 0.f;
  // prefetch
  int   sN = (r0 < r1) ? csr[r0] : 0;
  float aN = asrc[sN];
  float hN = bf2f(h2[(size_t)sN*C2 + lane]);
  for (int j = r0; j < r1; ++j){
    float aC = aN, hC = hN;
    if (j+1 < r1){
      int s = csr[j+1];
      aN = asrc[s];
      hN = bf2f(h2[(size_t)s*C2 + lane]);
    }
    float l = lrelu(aC + ad);
    float mn = fmaxf(m, l);
    float corr = __expf(m - mn);     // ==1 when m unchanged
    float w = __expf(l - mn);
    ss  = ss*corr + w;
    acc = acc*corr + w*hC;
    m = mn;
  }
  int g = batch[d];
  float v = acc/ss + bias[lane];
  atomicAdd(&pool[g*C2 + lane], v);
}

__global__ void cnt_kernel(const int* __restrict__ batch, int* __restrict__ cnt){
  int n = blockIdx.x*blockDim.x + threadIdx.x;
  if (n < N_NODES) atomicAdd(&cnt[batch[n]], 1);
}
__global__ void finalize_kernel(const float* __restrict__ sums, const int* __restrict__ cnt,
                                float* __restrict__ out){
  int i = blockIdx.x*blockDim.x + threadIdx.x;
  if (i >= G_GRAPHS*C2) return;
  int g = i >> 6;
  out[i] = sums[i] / fmaxf((float)cnt[g], 1.f);
}

// ---------- launch ----------
extern "C" void kernel_launch(void* const* d_in, const int* in_sizes, int n_in,
                              void* d_out, int out_size, void* d_ws, size_t ws_size,
                              hipStream_t stream) {
  const float* x        = (const float*)d_in[0];
  const int*   ei       = (const int*)  d_in[1];
  const int*   batch    = (const int*)  d_in[2];
  const float* W1       = (const float*)d_in[3];
  const float* att_src1 = (const float*)d_in[4];
  const float* att_dst1 = (const float*)d_in[5];
  const float* bias1    = (const float*)d_in[6];
  const float* W2       = (const float*)d_in[7];
  const float* att_src2 = (const float*)d_in[8];
  const float* att_dst2 = (const float*)d_in[9];
  const float* bias2    = (const float*)d_in[10];
  float* out = (float*)d_out;

  char* ws = (char*)d_ws;
  size_t o = 0;
  auto alloc = [&](size_t bytes)->size_t{ size_t r=o; o=(o+bytes+255)&~(size_t)255; return r; };

  size_t xb_o     = alloc((size_t)N_NODES*F_IN*2);   // 12.8 MB
  size_t w1t_o    = alloc((size_t)C1*F_IN*2);
  size_t w2t_o    = alloc((size_t)C2*C1*2);
  size_t wab_o    = alloc((size_t)32*F_IN*2);
  size_t asd_o    = alloc((size_t)N_NODES*32*4);     // 6.4 MB (src:0-11, dst:12-23)
  size_t out1_o   = alloc((size_t)N_NODES*C1*2);     // 38.4 MB
  size_t h2_o     = alloc((size_t)N_NODES*C2*2);     // 6.4 MB
  size_t asrc2_o  = alloc((size_t)N_NODES*4);
  size_t adst2_o  = alloc((size_t)N_NODES*4);
  size_t alpha1_o = alloc((size_t)ETOT*H1*4);        // 40.8 MB
  size_t zero_beg = o;
  size_t counts_o = alloc((size_t)N_NODES*4);
  size_t pool_o   = alloc((size_t)G_GRAPHS*C2*4);
  size_t cnt_o    = alloc((size_t)G_GRAPHS*4);
  size_t zero_end = o;
  size_t rowptr_o = alloc((size_t)(N_NODES+1)*4);
  size_t bsum_o   = alloc((size_t)NBLK_SCAN*4);
  size_t cursor_o = alloc((size_t)N_NODES*4);
  size_t csr_o    = alloc((size_t)ETOT*4);

  unsigned short* xb    = (unsigned short*)(ws + xb_o);
  unsigned short* w1t   = (unsigned short*)(ws + w1t_o);
  unsigned short* w2t   = (unsigned short*)(ws + w2t_o);
  unsigned short* wab   = (unsigned short*)(ws + wab_o);
  float* asd    = (float*)(ws + asd_o);
  unsigned short* out1b = (unsigned short*)(ws + out1_o);
  unsigned short* h2b   = (unsigned short*)(ws + h2_o);
  float* asrc2  = (float*)(ws + asrc2_o);
  float* adst2  = (float*)(ws + adst2_o);
  float* alpha1 = (float*)(ws + alpha1_o);
  int*   counts = (int*)  (ws + counts_o);
  float* poolf  = (float*)(ws + pool_o);
  int*   cnt    = (int*)  (ws + cnt_o);
  int*   rowptr = (int*)  (ws + rowptr_o);
  int*   bsum   = (int*)  (ws + bsum_o);
  int*   cursor = (int*)  (ws + cursor_o);
  int*   csrsrc = (int*)  (ws + csr_o);

  hipMemsetAsync(ws + zero_beg, 0, zero_end - zero_beg, stream);

  const int TPB = 256;
  int egrid = (ETOT + TPB - 1)/TPB;

  // prep
  cast_x_kernel<<<(N_NODES*F_IN/4 + TPB-1)/TPB, TPB, 0, stream>>>(x, xb);
  transpose_w_kernel<<<(F_IN*C1 + TPB-1)/TPB, TPB, 0, stream>>>(W1, w1t, F_IN, C1);
  transpose_w_kernel<<<(C1*C2 + TPB-1)/TPB, TPB, 0, stream>>>(W2, w2t, C1, C2);
  wab_prep<<<(32*F_IN + TPB-1)/TPB, TPB, 0, stream>>>(W1, att_src1, att_dst1, wab);

  // CSR build
  count_kernel<<<egrid, TPB, 0, stream>>>(ei, counts);
  scan_pass1<<<NBLK_SCAN, SCAN_B, 0, stream>>>(counts, rowptr, bsum);
  scan_pass2<<<1, 64, 0, stream>>>(bsum);
  scan_pass3<<<(N_NODES + TPB)/TPB, TPB, 0, stream>>>(rowptr, bsum, cursor);
  scatter_kernel<<<egrid, TPB, 0, stream>>>(ei, cursor, csrsrc);

  // conv1: logits GEMM -> alpha -> x-space agg + MFMA transform
  gemm_mfma<64,32,32,16,true><<<dim3((N_NODES+63)/64, 1), 256, 0, stream>>>(xb, wab, asd, N_NODES, 32, F_IN);
  alpha1_kernel<<<(N_NODES+3)/4, 256, 0, stream>>>(rowptr, csrsrc, asd, alpha1);
  agg1x2_kernel<<<N_NODES/16, 512, 0, stream>>>(rowptr, csrsrc, xb, alpha1, w1t, bias1, out1b);

  // conv2
  gemm_mfma<64,64,32,32,false><<<dim3((N_NODES+63)/64, 1), 256, 0, stream>>>(out1b, w2t, h2b, N_NODES, C2, C1);
  a2_kernel<<<(N_NODES + TPB-1)/TPB, TPB, 0, stream>>>(h2b, att_src2, att_dst2, asrc2, adst2);
  agg2o_kernel<<<(N_NODES+3)/4, 256, 0, stream>>>(rowptr, csrsrc, h2b, asrc2, adst2, bias2, batch, poolf);

  // pool finalize
  cnt_kernel<<<(N_NODES + TPB-1)/TPB, TPB, 0, stream>>>(batch, cnt);
  finalize_kernel<<<(G_GRAPHS*C2 + TPB-1)/TPB, TPB, 0, stream>>>(poolf, cnt, out);
}

// Round 8
// 469.062 us; speedup vs baseline: 1.1332x; 1.1309x over previous
//
#include <hip/hip_runtime.h>

#define N_NODES 50000
#define N_EDGES 800000
#define ETOT (N_EDGES + N_NODES)   // 850000
#define G_GRAPHS 256
#define F_IN 128
#define H1 12
#define D1 32
#define C1 (H1*D1)   // 384
#define C2 64
#define NEG 0.2f
#define SCAN_B 1024
#define NBLK_SCAN ((N_NODES + SCAN_B - 1)/SCAN_B)   // 49

using bf16x8  = __attribute__((ext_vector_type(8))) short;
using ushort8 = __attribute__((ext_vector_type(8))) unsigned short;
using f32x4   = __attribute__((ext_vector_type(4))) float;

__device__ __forceinline__ float lrelu(float x){ return x > 0.f ? x : NEG*x; }
__device__ __forceinline__ unsigned short f2bf(float f){
  unsigned u = __float_as_uint(f);
  u += 0x7fffu + ((u >> 16) & 1u);
  return (unsigned short)(u >> 16);
}
__device__ __forceinline__ float bf2f(unsigned short h){
  return __uint_as_float(((unsigned)h) << 16);
}

// ---------- prep ----------
__global__ void cast_x_kernel(const float* __restrict__ x, unsigned short* __restrict__ xb){
  int i = blockIdx.x*blockDim.x + threadIdx.x;
  int base = i*4;
  if (base >= N_NODES*F_IN) return;
  float4 v = *(const float4*)(x + base);
  ushort4 o; o.x=f2bf(v.x); o.y=f2bf(v.y); o.z=f2bf(v.z); o.w=f2bf(v.w);
  *(ushort4*)(xb + base) = o;
}
// W[K][Nc] fp32 -> Wt[Nc][K] bf16
__global__ void transpose_w_kernel(const float* __restrict__ W, unsigned short* __restrict__ Wt,
                                   int K, int Nc){
  int i = blockIdx.x*blockDim.x + threadIdx.x;
  if (i >= K*Nc) return;
  int n = i / K, k = i % K;
  Wt[i] = f2bf(W[(size_t)k*Nc + n]);
}
// wAb[c][k] bf16, c<12: W1·att_src (head c); 12<=c<24: W1·att_dst; else 0
__global__ void wab_prep(const float* __restrict__ W1, const float* __restrict__ att_src,
                         const float* __restrict__ att_dst, unsigned short* __restrict__ wAb){
  int i = blockIdx.x*blockDim.x + threadIdx.x;
  if (i >= 32*F_IN) return;
  int c = i >> 7, k = i & 127;
  float v = 0.f;
  if (c < 12){
    #pragma unroll
    for (int dd=0; dd<D1; ++dd) v += W1[(size_t)k*C1 + c*D1 + dd] * att_src[c*D1 + dd];
  } else if (c < 24){
    int h = c - 12;
    #pragma unroll
    for (int dd=0; dd<D1; ++dd) v += W1[(size_t)k*C1 + h*D1 + dd] * att_dst[h*D1 + dd];
  }
  wAb[i] = f2bf(v);
}

// ---------- bf16 MFMA GEMM: C[M][N] = A[M][K] @ Bt[N][K]^T ----------
template<int BM,int BN,int WM,int WN,bool F32OUT>
__global__ __launch_bounds__(256) void gemm_mfma(const unsigned short* __restrict__ A,
    const unsigned short* __restrict__ Bt, void* __restrict__ Cv,
    int M, int N, int K){
  constexpr int BK = 32;
  __shared__ unsigned short As2[4][BM][8];
  __shared__ unsigned short Bs2[4][BN][8];
  const int tid  = threadIdx.x;
  const int wid  = tid >> 6, lane = tid & 63;
  constexpr int NWX = BN / WN;
  const int wrow = (wid / NWX) * WM, wcol = (wid % NWX) * WN;
  constexpr int MR = WM/16, NR = WN/16;
  const int row0 = blockIdx.x * BM, col0 = blockIdx.y * BN;
  const int r = lane & 15, koct = lane >> 4;
  f32x4 acc[MR][NR];
  #pragma unroll
  for (int m=0;m<MR;m++)
    #pragma unroll
    for (int n=0;n<NR;n++) acc[m][n] = f32x4{0.f,0.f,0.f,0.f};

  for (int k0 = 0; k0 < K; k0 += BK){
    for (int s = tid; s < BM*8; s += 256){
      int rr = s >> 3, cc = (s & 7) * 4;
      int gr = row0 + rr;
      ushort4 v = (gr < M) ? *(const ushort4*)(A + (size_t)gr*K + k0 + cc)
                           : ushort4{0,0,0,0};
      *(ushort4*)(&As2[cc>>3][rr][cc&7]) = v;
    }
    for (int s = tid; s < BN*8; s += 256){
      int rr = s >> 3, cc = (s & 7) * 4;
      ushort4 v = *(const ushort4*)(Bt + (size_t)(col0+rr)*K + k0 + cc);
      *(ushort4*)(&Bs2[cc>>3][rr][cc&7]) = v;
    }
    __syncthreads();
    bf16x8 af[MR], bq[NR];
    #pragma unroll
    for (int m=0;m<MR;m++) af[m] = *(const bf16x8*)(&As2[koct][wrow + m*16 + r][0]);
    #pragma unroll
    for (int n=0;n<NR;n++) bq[n] = *(const bf16x8*)(&Bs2[koct][wcol + n*16 + r][0]);
    #pragma unroll
    for (int m=0;m<MR;m++)
      #pragma unroll
      for (int n=0;n<NR;n++)
        acc[m][n] = __builtin_amdgcn_mfma_f32_16x16x32_bf16(af[m], bq[n], acc[m][n], 0,0,0);
    __syncthreads();
  }
  #pragma unroll
  for (int m=0;m<MR;m++){
    #pragma unroll
    for (int rr=0; rr<4; rr++){
      int grow = row0 + wrow + m*16 + koct*4 + rr;
      if (grow < M){
        #pragma unroll
        for (int n=0;n<NR;n++){
          if constexpr (F32OUT)
            ((float*)Cv)[(size_t)grow*N + col0 + wcol + n*16 + r] = acc[m][n][rr];
          else
            ((unsigned short*)Cv)[(size_t)grow*N + col0 + wcol + n*16 + r] = f2bf(acc[m][n][rr]);
        }
      }
    }
  }
}

// ---------- CSR build ----------
__global__ void count_kernel(const int* __restrict__ ei, int* __restrict__ counts){
  int e = blockIdx.x*blockDim.x + threadIdx.x;
  if (e >= ETOT) return;
  int d = (e < N_EDGES) ? ei[N_EDGES + e] : (e - N_EDGES);
  atomicAdd(&counts[d], 1);
}
__global__ __launch_bounds__(SCAN_B) void scan_pass1(const int* __restrict__ counts,
    int* __restrict__ excl, int* __restrict__ bsum){
  __shared__ int sdata[SCAN_B];
  int i = blockIdx.x*SCAN_B + threadIdx.x;
  int v = (i < N_NODES) ? counts[i] : 0;
  sdata[threadIdx.x] = v;
  __syncthreads();
  for (int off=1; off<SCAN_B; off<<=1){
    int t = (threadIdx.x >= off) ? sdata[threadIdx.x-off] : 0;
    __syncthreads();
    sdata[threadIdx.x] += t;
    __syncthreads();
  }
  if (i < N_NODES) excl[i] = sdata[threadIdx.x] - v;
  if (threadIdx.x == SCAN_B-1) bsum[blockIdx.x] = sdata[SCAN_B-1];
}
__global__ void scan_pass2(int* __restrict__ bsum){
  if (threadIdx.x == 0){
    int acc = 0;
    for (int b=0;b<NBLK_SCAN;b++){ int t = bsum[b]; bsum[b] = acc; acc += t; }
  }
}
__global__ void scan_pass3(int* __restrict__ rowptr, const int* __restrict__ bsum,
                           int* __restrict__ cursor){
  int i = blockIdx.x*blockDim.x + threadIdx.x;
  if (i < N_NODES){
    int r = rowptr[i] + bsum[i/SCAN_B];
    rowptr[i] = r; cursor[i] = r;
  }
  if (i == N_NODES) rowptr[N_NODES] = ETOT;
}
__global__ void scatter_kernel(const int* __restrict__ ei, int* __restrict__ cursor,
                               int* __restrict__ csr_src){
  int e = blockIdx.x*blockDim.x + threadIdx.x;
  if (e >= ETOT) return;
  int s, d;
  if (e < N_EDGES){ s = ei[e]; d = ei[N_EDGES + e]; } else { s = d = e - N_EDGES; }
  int slot = atomicAdd(&cursor[d], 1);
  csr_src[slot] = s;
}

// ---------- alpha (conv1, 12 heads): 1 wave per dst, 4 dst/block ----------
__global__ __launch_bounds__(256) void alpha1_kernel(const int* __restrict__ rowptr,
    const int* __restrict__ csr, const float* __restrict__ asd,
    float* __restrict__ alpha){
  int d = blockIdx.x*4 + (threadIdx.x >> 6);
  int lane = threadIdx.x & 63;
  int r0 = rowptr[d], r1 = rowptr[d+1], deg = r1 - r0;
  float4 ad0 = *(const float4*)(asd + (size_t)d*32 + 12);
  float4 ad1 = *(const float4*)(asd + (size_t)d*32 + 16);
  float4 ad2 = *(const float4*)(asd + (size_t)d*32 + 20);
  float ad[12] = {ad0.x,ad0.y,ad0.z,ad0.w, ad1.x,ad1.y,ad1.z,ad1.w, ad2.x,ad2.y,ad2.z,ad2.w};

  if (deg <= 64){
    bool act = lane < deg;
    int j = r0 + lane;
    int s = act ? csr[j] : 0;
    float4 s0 = *(const float4*)(asd + (size_t)s*32);
    float4 s1 = *(const float4*)(asd + (size_t)s*32 + 4);
    float4 s2 = *(const float4*)(asd + (size_t)s*32 + 8);
    float as[12] = {s0.x,s0.y,s0.z,s0.w, s1.x,s1.y,s1.z,s1.w, s2.x,s2.y,s2.z,s2.w};
    float w[12];
    #pragma unroll
    for (int h=0; h<12; ++h){
      float l = act ? lrelu(as[h] + ad[h]) : -1e30f;
      float m = l;
      #pragma unroll
      for (int off=32; off; off>>=1) m = fmaxf(m, __shfl_xor(m, off));
      float wv = act ? __expf(l - m) : 0.f;
      float ss = wv;
      #pragma unroll
      for (int off=32; off; off>>=1) ss += __shfl_xor(ss, off);
      w[h] = wv / ss;
    }
    if (act){
      *(float4*)(alpha + (size_t)j*12)     = float4{w[0],w[1],w[2],w[3]};
      *(float4*)(alpha + (size_t)j*12 + 4) = float4{w[4],w[5],w[6],w[7]};
      *(float4*)(alpha + (size_t)j*12 + 8) = float4{w[8],w[9],w[10],w[11]};
    }
  } else {
    float mx[12], ss[12];
    #pragma unroll
    for (int h=0;h<12;h++){ mx[h] = -1e30f; ss[h] = 0.f; }
    for (int j = r0 + lane; j < r1; j += 64){
      int s = csr[j];
      float4 s0 = *(const float4*)(asd + (size_t)s*32);
      float4 s1 = *(const float4*)(asd + (size_t)s*32 + 4);
      float4 s2 = *(const float4*)(asd + (size_t)s*32 + 8);
      float as[12] = {s0.x,s0.y,s0.z,s0.w, s1.x,s1.y,s1.z,s1.w, s2.x,s2.y,s2.z,s2.w};
      #pragma unroll
      for (int h=0;h<12;h++) mx[h] = fmaxf(mx[h], lrelu(as[h] + ad[h]));
    }
    #pragma unroll
    for (int h=0;h<12;h++){
      #pragma unroll
      for (int off=32; off; off>>=1) mx[h] = fmaxf(mx[h], __shfl_xor(mx[h], off));
    }
    for (int j = r0 + lane; j < r1; j += 64){
      int s = csr[j];
      float4 s0 = *(const float4*)(asd + (size_t)s*32);
      float4 s1 = *(const float4*)(asd + (size_t)s*32 + 4);
      float4 s2 = *(const float4*)(asd + (size_t)s*32 + 8);
      float as[12] = {s0.x,s0.y,s0.z,s0.w, s1.x,s1.y,s1.z,s1.w, s2.x,s2.y,s2.z,s2.w};
      float w[12];
      #pragma unroll
      for (int h=0;h<12;h++){ w[h] = __expf(lrelu(as[h]+ad[h]) - mx[h]); ss[h] += w[h]; }
      *(float4*)(alpha + (size_t)j*12)     = float4{w[0],w[1],w[2],w[3]};
      *(float4*)(alpha + (size_t)j*12 + 4) = float4{w[4],w[5],w[6],w[7]};
      *(float4*)(alpha + (size_t)j*12 + 8) = float4{w[8],w[9],w[10],w[11]};
    }
    float inv[12];
    #pragma unroll
    for (int h=0;h<12;h++){
      #pragma unroll
      for (int off=32; off; off>>=1) ss[h] += __shfl_xor(ss[h], off);
      inv[h] = 1.f / ss[h];
    }
    for (int j = r0 + lane; j < r1; j += 64){
      float4 o0 = *(const float4*)(alpha + (size_t)j*12);
      float4 o1 = *(const float4*)(alpha + (size_t)j*12 + 4);
      float4 o2 = *(const float4*)(alpha + (size_t)j*12 + 8);
      o0.x*=inv[0]; o0.y*=inv[1]; o0.z*=inv[2]; o0.w*=inv[3];
      o1.x*=inv[4]; o1.y*=inv[5]; o1.z*=inv[6]; o1.w*=inv[7];
      o2.x*=inv[8]; o2.y*=inv[9]; o2.z*=inv[10]; o2.w*=inv[11];
      *(float4*)(alpha + (size_t)j*12)     = o0;
      *(float4*)(alpha + (size_t)j*12 + 4) = o1;
      *(float4*)(alpha + (size_t)j*12 + 8) = o2;
    }
  }
}

// ---------- conv1: chunk-staged x-space aggregation + MFMA transform ----------
// 256 thr = 4 waves = 16 dst/block, 16 lanes/dst. 16-edge chunks:
// lane t stages edge t's csr (reg, shfl-broadcast) + alpha (LDS broadcast).
// x rows: ushort8 with 2-deep prefetch. Epilogue: per-head MFMA (2 halves).
__global__ __launch_bounds__(256) void agg1c_kernel(const int* __restrict__ rowptr,
    const int* __restrict__ csr, const unsigned short* __restrict__ xb,
    const float* __restrict__ alpha, const unsigned short* __restrict__ w1t,
    const float* __restrict__ bias, unsigned short* __restrict__ out1){
  constexpr int ROWE = 6*F_IN + 8;            // 776 ushorts
  constexpr int WROW = 16*12 + 4;             // 196 floats (pad 4: bank-shift per slot)
  __shared__ unsigned short agg[16*ROWE];     // 24832 B
  __shared__ float wlds[16][WROW];            // 12544 B

  const int tid  = threadIdx.x;
  const int slot = tid >> 4;                  // 0..15 dst in block
  const int t16  = tid & 15;
  const int base = ((tid & 63) >> 4) * 16;    // wave-lane base of this dst group
  const int d    = blockIdx.x*16 + slot;
  const int r0 = rowptr[d], r1 = rowptr[d+1];

  float acc[12][8];
  #pragma unroll
  for (int h=0;h<12;h++)
    #pragma unroll
    for (int i=0;i<8;i++) acc[h][i] = 0.f;

  for (int c0 = r0; c0 < r1; c0 += 16){
    int nc = min(16, r1 - c0);
    // stage: lane t -> edge c0+t
    int s_st = 0;
    if (t16 < nc){
      int j = c0 + t16;
      s_st = csr[j];
      float4 a0 = *(const float4*)(alpha + (size_t)j*12);
      float4 a1 = *(const float4*)(alpha + (size_t)j*12 + 4);
      float4 a2 = *(const float4*)(alpha + (size_t)j*12 + 8);
      *(float4*)(&wlds[slot][t16*12 + 0]) = a0;
      *(float4*)(&wlds[slot][t16*12 + 4]) = a1;
      *(float4*)(&wlds[slot][t16*12 + 8]) = a2;
    }
    __builtin_amdgcn_wave_barrier();
    // 2-deep x prefetch (s via shfl from staged regs)
    int sA = __shfl(s_st, base + 0);
    ushort8 xA = *(const ushort8*)(xb + (size_t)sA*F_IN + t16*8);
    ushort8 xB = {0,0,0,0,0,0,0,0};
    if (nc > 1){
      int sB = __shfl(s_st, base + 1);
      xB = *(const ushort8*)(xb + (size_t)sB*F_IN + t16*8);
    }
    for (int e = 0; e < nc; ++e){
      ushort8 cx = xA;
      xA = xB;
      if (e + 2 < nc){
        int sN = __shfl(s_st, base + e + 2);
        xB = *(const ushort8*)(xb + (size_t)sN*F_IN + t16*8);
      }
      float4 w0 = *(const float4*)(&wlds[slot][e*12 + 0]);
      float4 w1 = *(const float4*)(&wlds[slot][e*12 + 4]);
      float4 w2 = *(const float4*)(&wlds[slot][e*12 + 8]);
      float xf[8];
      #pragma unroll
      for (int i=0;i<8;i++) xf[i] = bf2f((unsigned short)cx[i]);
      float w[12] = {w0.x,w0.y,w0.z,w0.w, w1.x,w1.y,w1.z,w1.w, w2.x,w2.y,w2.z,w2.w};
      #pragma unroll
      for (int h=0;h<12;h++)
        #pragma unroll
        for (int i=0;i<8;i++) acc[h][i] += w[h]*xf[i];
    }
    __builtin_amdgcn_wave_barrier();
  }

  // ---- epilogue: agg(bf16, LDS) @ W1 per head, two halves of 6 heads ----
  const int wv = tid >> 6, lane = tid & 63;
  const int er = lane & 15, eq = lane >> 4;
  #pragma unroll
  for (int hf = 0; hf < 2; ++hf){
    __syncthreads();   // prev half's MFMA reads complete before overwrite
    #pragma unroll
    for (int h = 0; h < 6; ++h){
      int hh = hf*6 + h;
      ushort8 v;
      #pragma unroll
      for (int i=0;i<8;i++) v[i] = f2bf(acc[hh][i]);
      *(ushort8*)(&agg[slot*ROWE + h*F_IN + t16*8]) = v;
    }
    __syncthreads();
    for (int tt = wv; tt < 12; tt += 4){
      int h = tt >> 1, nb = tt & 1;
      int hh = hf*6 + h;
      f32x4 c = {0.f,0.f,0.f,0.f};
      #pragma unroll
      for (int kk=0; kk<4; ++kk){
        bf16x8 af = *(const bf16x8*)(&agg[er*ROWE + h*F_IN + kk*32 + eq*8]);
        bf16x8 bq = *(const bf16x8*)(w1t + (size_t)(hh*32 + nb*16 + er)*F_IN + kk*32 + eq*8);
        c = __builtin_amdgcn_mfma_f32_16x16x32_bf16(af, bq, c, 0,0,0);
      }
      int col = hh*32 + nb*16 + er;
      float bv = bias[col];
      #pragma unroll
      for (int rr=0; rr<4; ++rr){
        int od = blockIdx.x*16 + eq*4 + rr;
        out1[(size_t)od*C1 + col] = f2bf(fmaxf(c[rr] + bv, 0.f));
      }
    }
  }
}

// ---------- per-node attention halves, conv2 ----------
__global__ void a2_kernel(const unsigned short* __restrict__ h2,
    const float* __restrict__ att_src, const float* __restrict__ att_dst,
    float* __restrict__ a_src, float* __restrict__ a_dst){
  int n = blockIdx.x*blockDim.x + threadIdx.x;
  if (n >= N_NODES) return;
  const unsigned short* hp = h2 + (size_t)n*C2;
  float s=0.f, d=0.f;
  #pragma unroll
  for (int k4=0;k4<16;k4++){
    ushort4 v = *(const ushort4*)(hp + k4*4);
    int b = k4*4;
    s += bf2f(v.x)*att_src[b] + bf2f(v.y)*att_src[b+1] + bf2f(v.z)*att_src[b+2] + bf2f(v.w)*att_src[b+3];
    d += bf2f(v.x)*att_dst[b] + bf2f(v.y)*att_dst[b+1] + bf2f(v.z)*att_dst[b+2] + bf2f(v.w)*att_dst[b+3];
  }
  a_src[n]=s; a_dst[n]=d;
}

// ---------- conv2: chunk-staged online softmax + aggregation + pool atomics ----------
// 256 thr = 16 dst/block, 16 lanes/dst (4 feats each), shfl-broadcast s/a, 2-deep prefetch.
__global__ __launch_bounds__(256) void agg2c_kernel(const int* __restrict__ rowptr,
    const int* __restrict__ csr, const unsigned short* __restrict__ h2,
    const float* __restrict__ asrc, const float* __restrict__ adst,
    const float* __restrict__ bias, const int* __restrict__ batch,
    float* __restrict__ pool){
  const int tid  = threadIdx.x;
  const int slot = tid >> 4;
  const int t16  = tid & 15;
  const int base = ((tid & 63) >> 4) * 16;
  const int d    = blockIdx.x*16 + slot;
  const int r0 = rowptr[d], r1 = rowptr[d+1];
  const float ad = adst[d];

  float m = -1e30f, ss = 0.f;
  float a0=0.f, a1=0.f, a2=0.f, a3=0.f;

  for (int c0 = r0; c0 < r1; c0 += 16){
    int nc = min(16, r1 - c0);
    int s_st = 0; float al_st = 0.f;
    if (t16 < nc){
      s_st = csr[c0 + t16];
      al_st = asrc[s_st];
    }
    int sA = __shfl(s_st, base + 0);
    ushort4 xA = *(const ushort4*)(h2 + (size_t)sA*C2 + t16*4);
    ushort4 xB = {0,0,0,0};
    if (nc > 1){
      int sB = __shfl(s_st, base + 1);
      xB = *(const ushort4*)(h2 + (size_t)sB*C2 + t16*4);
    }
    for (int e = 0; e < nc; ++e){
      ushort4 cx = xA;
      xA = xB;
      if (e + 2 < nc){
        int sN = __shfl(s_st, base + e + 2);
        xB = *(const ushort4*)(h2 + (size_t)sN*C2 + t16*4);
      }
      float a = __shfl(al_st, base + e);
      float l = lrelu(a + ad);
      float mn = fmaxf(m, l);
      float corr = __expf(m - mn);
      float w = __expf(l - mn);
      ss = ss*corr + w;
      a0 = a0*corr + w*bf2f(cx.x);
      a1 = a1*corr + w*bf2f(cx.y);
      a2 = a2*corr + w*bf2f(cx.z);
      a3 = a3*corr + w*bf2f(cx.w);
      m = mn;
    }
  }
  float inv = 1.f / ss;
  int g = batch[d];
  int fb = t16*4;
  atomicAdd(&pool[g*C2 + fb+0], a0*inv + bias[fb+0]);
  atomicAdd(&pool[g*C2 + fb+1], a1*inv + bias[fb+1]);
  atomicAdd(&pool[g*C2 + fb+2], a2*inv + bias[fb+2]);
  atomicAdd(&pool[g*C2 + fb+3], a3*inv + bias[fb+3]);
}

__global__ void cnt_kernel(const int* __restrict__ batch, int* __restrict__ cnt){
  int n = blockIdx.x*blockDim.x + threadIdx.x;
  if (n < N_NODES) atomicAdd(&cnt[batch[n]], 1);
}
__global__ void finalize_kernel(const float* __restrict__ sums, const int* __restrict__ cnt,
                                float* __restrict__ out){
  int i = blockIdx.x*blockDim.x + threadIdx.x;
  if (i >= G_GRAPHS*C2) return;
  int g = i >> 6;
  out[i] = sums[i] / fmaxf((float)cnt[g], 1.f);
}

// ---------- launch ----------
extern "C" void kernel_launch(void* const* d_in, const int* in_sizes, int n_in,
                              void* d_out, int out_size, void* d_ws, size_t ws_size,
                              hipStream_t stream) {
  const float* x        = (const float*)d_in[0];
  const int*   ei       = (const int*)  d_in[1];
  const int*   batch    = (const int*)  d_in[2];
  const float* W1       = (const float*)d_in[3];
  const float* att_src1 = (const float*)d_in[4];
  const float* att_dst1 = (const float*)d_in[5];
  const float* bias1    = (const float*)d_in[6];
  const float* W2       = (const float*)d_in[7];
  const float* att_src2 = (const float*)d_in[8];
  const float* att_dst2 = (const float*)d_in[9];
  const float* bias2    = (const float*)d_in[10];
  float* out = (float*)d_out;

  char* ws = (char*)d_ws;
  size_t o = 0;
  auto alloc = [&](size_t bytes)->size_t{ size_t r=o; o=(o+bytes+255)&~(size_t)255; return r; };

  size_t xb_o     = alloc((size_t)N_NODES*F_IN*2);   // 12.8 MB
  size_t w1t_o    = alloc((size_t)C1*F_IN*2);
  size_t w2t_o    = alloc((size_t)C2*C1*2);
  size_t wab_o    = alloc((size_t)32*F_IN*2);
  size_t asd_o    = alloc((size_t)N_NODES*32*4);     // 6.4 MB (src:0-11, dst:12-23)
  size_t out1_o   = alloc((size_t)N_NODES*C1*2);     // 38.4 MB
  size_t h2_o     = alloc((size_t)N_NODES*C2*2);     // 6.4 MB
  size_t asrc2_o  = alloc((size_t)N_NODES*4);
  size_t adst2_o  = alloc((size_t)N_NODES*4);
  size_t alpha1_o = alloc((size_t)ETOT*H1*4);        // 40.8 MB
  size_t zero_beg = o;
  size_t counts_o = alloc((size_t)N_NODES*4);
  size_t pool_o   = alloc((size_t)G_GRAPHS*C2*4);
  size_t cnt_o    = alloc((size_t)G_GRAPHS*4);
  size_t zero_end = o;
  size_t rowptr_o = alloc((size_t)(N_NODES+1)*4);
  size_t bsum_o   = alloc((size_t)NBLK_SCAN*4);
  size_t cursor_o = alloc((size_t)N_NODES*4);
  size_t csr_o    = alloc((size_t)ETOT*4);

  unsigned short* xb    = (unsigned short*)(ws + xb_o);
  unsigned short* w1t   = (unsigned short*)(ws + w1t_o);
  unsigned short* w2t   = (unsigned short*)(ws + w2t_o);
  unsigned short* wab   = (unsigned short*)(ws + wab_o);
  float* asd    = (float*)(ws + asd_o);
  unsigned short* out1b = (unsigned short*)(ws + out1_o);
  unsigned short* h2b   = (unsigned short*)(ws + h2_o);
  float* asrc2  = (float*)(ws + asrc2_o);
  float* adst2  = (float*)(ws + adst2_o);
  float* alpha1 = (float*)(ws + alpha1_o);
  int*   counts = (int*)  (ws + counts_o);
  float* poolf  = (float*)(ws + pool_o);
  int*   cnt    = (int*)  (ws + cnt_o);
  int*   rowptr = (int*)  (ws + rowptr_o);
  int*   bsum   = (int*)  (ws + bsum_o);
  int*   cursor = (int*)  (ws + cursor_o);
  int*   csrsrc = (int*)  (ws + csr_o);

  hipMemsetAsync(ws + zero_beg, 0, zero_end - zero_beg, stream);

  const int TPB = 256;
  int egrid = (ETOT + TPB - 1)/TPB;

  // prep
  cast_x_kernel<<<(N_NODES*F_IN/4 + TPB-1)/TPB, TPB, 0, stream>>>(x, xb);
  transpose_w_kernel<<<(F_IN*C1 + TPB-1)/TPB, TPB, 0, stream>>>(W1, w1t, F_IN, C1);
  transpose_w_kernel<<<(C1*C2 + TPB-1)/TPB, TPB, 0, stream>>>(W2, w2t, C1, C2);
  wab_prep<<<(32*F_IN + TPB-1)/TPB, TPB, 0, stream>>>(W1, att_src1, att_dst1, wab);

  // CSR build
  count_kernel<<<egrid, TPB, 0, stream>>>(ei, counts);
  scan_pass1<<<NBLK_SCAN, SCAN_B, 0, stream>>>(counts, rowptr, bsum);
  scan_pass2<<<1, 64, 0, stream>>>(bsum);
  scan_pass3<<<(N_NODES + TPB)/TPB, TPB, 0, stream>>>(rowptr, bsum, cursor);
  scatter_kernel<<<egrid, TPB, 0, stream>>>(ei, cursor, csrsrc);

  // conv1: logits GEMM -> alpha -> chunk-staged agg + MFMA transform
  gemm_mfma<64,32,32,16,true><<<dim3((N_NODES+63)/64, 1), 256, 0, stream>>>(xb, wab, asd, N_NODES, 32, F_IN);
  alpha1_kernel<<<(N_NODES+3)/4, 256, 0, stream>>>(rowptr, csrsrc, asd, alpha1);
  agg1c_kernel<<<N_NODES/16, 256, 0, stream>>>(rowptr, csrsrc, xb, alpha1, w1t, bias1, out1b);

  // conv2
  gemm_mfma<64,64,32,32,false><<<dim3((N_NODES+63)/64, 1), 256, 0, stream>>>(out1b, w2t, h2b, N_NODES, C2, C1);
  a2_kernel<<<(N_NODES + TPB-1)/TPB, TPB, 0, stream>>>(h2b, att_src2, att_dst2, asrc2, adst2);
  agg2c_kernel<<<(N_NODES+15)/16, 256, 0, stream>>>(rowptr, csrsrc, h2b, asrc2, adst2, bias2, batch, poolf);

  // pool finalize
  cnt_kernel<<<(N_NODES + TPB-1)/TPB, TPB, 0, stream>>>(batch, cnt);
  finalize_kernel<<<(G_GRAPHS*C2 + TPB-1)/TPB, TPB, 0, stream>>>(poolf, cnt, out);
}

// Round 9
// 442.130 us; speedup vs baseline: 1.2022x; 1.0609x over previous
//
#include <hip/hip_runtime.h>

#define N_NODES 50000
#define N_EDGES 800000
#define ETOT (N_EDGES + N_NODES)   // 850000
#define G_GRAPHS 256
#define F_IN 128
#define H1 12
#define D1 32
#define C1 (H1*D1)   // 384
#define C2 64
#define NEG 0.2f
#define SCAN_B 1024
#define NBLK_SCAN ((N_NODES + SCAN_B - 1)/SCAN_B)   // 49

using bf16x8  = __attribute__((ext_vector_type(8))) short;
using ushort8 = __attribute__((ext_vector_type(8))) unsigned short;
using f32x4   = __attribute__((ext_vector_type(4))) float;

__device__ __forceinline__ float lrelu(float x){ return x > 0.f ? x : NEG*x; }
__device__ __forceinline__ unsigned short f2bf(float f){
  unsigned u = __float_as_uint(f);
  u += 0x7fffu + ((u >> 16) & 1u);
  return (unsigned short)(u >> 16);
}
__device__ __forceinline__ float bf2f(unsigned short h){
  return __uint_as_float(((unsigned)h) << 16);
}
// exp without max-subtraction; clamp is an overflow guard only (never hit for |l|<=30)
__device__ __forceinline__ float wexp(float l){ return __expf(fminf(l, 30.f)); }

// ---------- merged prep: cast x, transpose W1/W2, build wAb ----------
#define B_CAST ((N_NODES*F_IN/4 + 255)/256)   // 6250
#define B_W1   ((F_IN*C1 + 255)/256)          // 192
#define B_W2   ((C1*C2 + 255)/256)            // 96
#define B_WAB  ((32*F_IN + 255)/256)          // 16
__global__ void prep_kernel(const float* __restrict__ x, const float* __restrict__ W1,
    const float* __restrict__ W2, const float* __restrict__ att_src,
    const float* __restrict__ att_dst, unsigned short* __restrict__ xb,
    unsigned short* __restrict__ w1t, unsigned short* __restrict__ w2t,
    unsigned short* __restrict__ wAb){
  int b = blockIdx.x, tid = threadIdx.x;
  if (b < B_CAST){
    int base = (b*256 + tid)*4;
    if (base >= N_NODES*F_IN) return;
    float4 v = *(const float4*)(x + base);
    ushort4 o; o.x=f2bf(v.x); o.y=f2bf(v.y); o.z=f2bf(v.z); o.w=f2bf(v.w);
    *(ushort4*)(xb + base) = o;
  } else if (b < B_CAST + B_W1){
    int i = (b - B_CAST)*256 + tid;
    if (i >= F_IN*C1) return;
    int n = i / F_IN, k = i % F_IN;
    w1t[i] = f2bf(W1[(size_t)k*C1 + n]);
  } else if (b < B_CAST + B_W1 + B_W2){
    int i = (b - B_CAST - B_W1)*256 + tid;
    if (i >= C1*C2) return;
    int n = i / C1, k = i % C1;
    w2t[i] = f2bf(W2[(size_t)k*C2 + n]);
  } else {
    int i = (b - B_CAST - B_W1 - B_W2)*256 + tid;
    if (i >= 32*F_IN) return;
    int c = i >> 7, k = i & 127;
    float v = 0.f;
    if (c < 12){
      #pragma unroll
      for (int dd=0; dd<D1; ++dd) v += W1[(size_t)k*C1 + c*D1 + dd] * att_src[c*D1 + dd];
    } else if (c < 24){
      int h = c - 12;
      #pragma unroll
      for (int dd=0; dd<D1; ++dd) v += W1[(size_t)k*C1 + h*D1 + dd] * att_dst[h*D1 + dd];
    }
    wAb[i] = f2bf(v);
  }
}

// ---------- bf16 MFMA GEMM: C[M][N] = A[M][K] @ Bt[N][K]^T ----------
template<int BM,int BN,int WM,int WN,bool F32OUT>
__global__ __launch_bounds__(256) void gemm_mfma(const unsigned short* __restrict__ A,
    const unsigned short* __restrict__ Bt, void* __restrict__ Cv,
    int M, int N, int K){
  constexpr int BK = 32;
  __shared__ unsigned short As2[4][BM][8];
  __shared__ unsigned short Bs2[4][BN][8];
  const int tid  = threadIdx.x;
  const int wid  = tid >> 6, lane = tid & 63;
  constexpr int NWX = BN / WN;
  const int wrow = (wid / NWX) * WM, wcol = (wid % NWX) * WN;
  constexpr int MR = WM/16, NR = WN/16;
  const int row0 = blockIdx.x * BM, col0 = blockIdx.y * BN;
  const int r = lane & 15, koct = lane >> 4;
  f32x4 acc[MR][NR];
  #pragma unroll
  for (int m=0;m<MR;m++)
    #pragma unroll
    for (int n=0;n<NR;n++) acc[m][n] = f32x4{0.f,0.f,0.f,0.f};

  for (int k0 = 0; k0 < K; k0 += BK){
    for (int s = tid; s < BM*8; s += 256){
      int rr = s >> 3, cc = (s & 7) * 4;
      int gr = row0 + rr;
      ushort4 v = (gr < M) ? *(const ushort4*)(A + (size_t)gr*K + k0 + cc)
                           : ushort4{0,0,0,0};
      *(ushort4*)(&As2[cc>>3][rr][cc&7]) = v;
    }
    for (int s = tid; s < BN*8; s += 256){
      int rr = s >> 3, cc = (s & 7) * 4;
      ushort4 v = *(const ushort4*)(Bt + (size_t)(col0+rr)*K + k0 + cc);
      *(ushort4*)(&Bs2[cc>>3][rr][cc&7]) = v;
    }
    __syncthreads();
    bf16x8 af[MR], bq[NR];
    #pragma unroll
    for (int m=0;m<MR;m++) af[m] = *(const bf16x8*)(&As2[koct][wrow + m*16 + r][0]);
    #pragma unroll
    for (int n=0;n<NR;n++) bq[n] = *(const bf16x8*)(&Bs2[koct][wcol + n*16 + r][0]);
    #pragma unroll
    for (int m=0;m<MR;m++)
      #pragma unroll
      for (int n=0;n<NR;n++)
        acc[m][n] = __builtin_amdgcn_mfma_f32_16x16x32_bf16(af[m], bq[n], acc[m][n], 0,0,0);
    __syncthreads();
  }
  #pragma unroll
  for (int m=0;m<MR;m++){
    #pragma unroll
    for (int rr=0; rr<4; rr++){
      int grow = row0 + wrow + m*16 + koct*4 + rr;
      if (grow < M){
        #pragma unroll
        for (int n=0;n<NR;n++){
          if constexpr (F32OUT)
            ((float*)Cv)[(size_t)grow*N + col0 + wcol + n*16 + r] = acc[m][n][rr];
          else
            ((unsigned short*)Cv)[(size_t)grow*N + col0 + wcol + n*16 + r] = f2bf(acc[m][n][rr]);
        }
      }
    }
  }
}

// ---------- CSR build ----------
#define EGRID ((ETOT + 255)/256)          // 3321
#define NGRID ((N_NODES + 255)/256)       // 196
__global__ void count_cnt_kernel(const int* __restrict__ ei, const int* __restrict__ batch,
                                 int* __restrict__ counts, int* __restrict__ cnt){
  if ((int)blockIdx.x < EGRID){
    int e = blockIdx.x*256 + threadIdx.x;
    if (e >= ETOT) return;
    int d = (e < N_EDGES) ? ei[N_EDGES + e] : (e - N_EDGES);
    atomicAdd(&counts[d], 1);
  } else {
    int n = (blockIdx.x - EGRID)*256 + threadIdx.x;
    if (n < N_NODES) atomicAdd(&cnt[batch[n]], 1);
  }
}
__global__ __launch_bounds__(SCAN_B) void scan_pass1(const int* __restrict__ counts,
    int* __restrict__ excl, int* __restrict__ bsum){
  __shared__ int sdata[SCAN_B];
  int i = blockIdx.x*SCAN_B + threadIdx.x;
  int v = (i < N_NODES) ? counts[i] : 0;
  sdata[threadIdx.x] = v;
  __syncthreads();
  for (int off=1; off<SCAN_B; off<<=1){
    int t = (threadIdx.x >= off) ? sdata[threadIdx.x-off] : 0;
    __syncthreads();
    sdata[threadIdx.x] += t;
    __syncthreads();
  }
  if (i < N_NODES) excl[i] = sdata[threadIdx.x] - v;
  if (threadIdx.x == SCAN_B-1) bsum[blockIdx.x] = sdata[SCAN_B-1];
}
// pass2 merged: each block computes its own carry from raw bsum
__global__ void scan_pass3(int* __restrict__ rowptr, const int* __restrict__ bsum,
                           int* __restrict__ cursor){
  __shared__ int carry_s;
  int sblk = blockIdx.x >> 2;       // 256-thread block -> which 1024-scan-block
  if (threadIdx.x == 0){
    int c = 0;
    for (int b=0; b<sblk; ++b) c += bsum[b];
    carry_s = c;
  }
  __syncthreads();
  int i = blockIdx.x*256 + (int)threadIdx.x;
  if (i < N_NODES){
    int r = rowptr[i] + carry_s;
    rowptr[i] = r; cursor[i] = r;
  }
  if (i == N_NODES) rowptr[N_NODES] = ETOT;
}
__global__ void scatter_kernel(const int* __restrict__ ei, int* __restrict__ cursor,
                               int* __restrict__ csr_src){
  int e = blockIdx.x*blockDim.x + threadIdx.x;
  if (e >= ETOT) return;
  int s, d;
  if (e < N_EDGES){ s = ei[e]; d = ei[N_EDGES + e]; } else { s = d = e - N_EDGES; }
  int slot = atomicAdd(&cursor[d], 1);
  csr_src[slot] = s;
}

// ---------- conv1 fused: no-max softmax + x-space aggregation + MFMA transform ----------
// 512 thr = 8 waves = 16 dst/block, 32 lanes/dst. Head-split: lanes 0-15 heads 0-5,
// lanes 16-31 heads 6-11; each lane 8 feats -> acc[6][8] = 48 regs.
// 32-edge chunks: lane e stages edge e's csr + w[12]=exp(l) (no max) into LDS.
__global__ __launch_bounds__(512) void agg1s_kernel(const int* __restrict__ rowptr,
    const int* __restrict__ csr, const unsigned short* __restrict__ xb,
    const float* __restrict__ asd, const unsigned short* __restrict__ w1t,
    const float* __restrict__ bias, unsigned short* __restrict__ out1){
  constexpr int ROWE = 6*F_IN + 8;            // 776 ushorts
  constexpr int WROW = 32*12 + 4;             // 388 floats
  __shared__ unsigned short agg[16*ROWE];     // 24832 B
  __shared__ float wlds[16][WROW];            // 24832 B

  const int tid    = threadIdx.x;
  const int slot   = tid >> 5;                // 0..15 dst in block
  const int lane32 = tid & 31;
  const int h16    = lane32 >> 4;             // head half (0: h0-5, 1: h6-11)
  const int t16    = lane32 & 15;             // feature chunk (8 bf16)
  const int gbase  = tid & 32;                // 32-lane group base within wave
  const int d      = blockIdx.x*16 + slot;
  const int r0 = rowptr[d], r1 = rowptr[d+1];

  float4 ad0 = *(const float4*)(asd + (size_t)d*32 + 12);
  float4 ad1 = *(const float4*)(asd + (size_t)d*32 + 16);
  float4 ad2 = *(const float4*)(asd + (size_t)d*32 + 20);
  float ad[12] = {ad0.x,ad0.y,ad0.z,ad0.w, ad1.x,ad1.y,ad1.z,ad1.w, ad2.x,ad2.y,ad2.z,ad2.w};

  float acc[6][8];
  #pragma unroll
  for (int h=0;h<6;h++)
    #pragma unroll
    for (int i=0;i<8;i++) acc[h][i] = 0.f;
  float ss[12];
  #pragma unroll
  for (int h=0;h<12;h++) ss[h] = 0.f;

  for (int c0 = r0; c0 < r1; c0 += 32){
    int nc = min(32, r1 - c0);
    int s_st = 0;
    if (lane32 < nc){
      int j = c0 + lane32;
      s_st = csr[j];
      float4 s0 = *(const float4*)(asd + (size_t)s_st*32);
      float4 s1 = *(const float4*)(asd + (size_t)s_st*32 + 4);
      float4 s2 = *(const float4*)(asd + (size_t)s_st*32 + 8);
      float as[12] = {s0.x,s0.y,s0.z,s0.w, s1.x,s1.y,s1.z,s1.w, s2.x,s2.y,s2.z,s2.w};
      float w[12];
      #pragma unroll
      for (int h=0;h<12;h++){ w[h] = wexp(lrelu(as[h] + ad[h])); ss[h] += w[h]; }
      *(float4*)(&wlds[slot][lane32*12 + 0]) = float4{w[0],w[1],w[2],w[3]};
      *(float4*)(&wlds[slot][lane32*12 + 4]) = float4{w[4],w[5],w[6],w[7]};
      *(float4*)(&wlds[slot][lane32*12 + 8]) = float4{w[8],w[9],w[10],w[11]};
    }
    __builtin_amdgcn_wave_barrier();
    int sA = __shfl(s_st, gbase + 0);
    ushort8 xA = *(const ushort8*)(xb + (size_t)sA*F_IN + t16*8);
    ushort8 xB = {0,0,0,0,0,0,0,0};
    if (nc > 1){
      int sB = __shfl(s_st, gbase + 1);
      xB = *(const ushort8*)(xb + (size_t)sB*F_IN + t16*8);
    }
    for (int e = 0; e < nc; ++e){
      ushort8 cx = xA;
      xA = xB;
      if (e + 2 < nc){
        int sN = __shfl(s_st, gbase + e + 2);
        xB = *(const ushort8*)(xb + (size_t)sN*F_IN + t16*8);
      }
      float2 w0 = *(const float2*)(&wlds[slot][e*12 + h16*6 + 0]);
      float2 w1 = *(const float2*)(&wlds[slot][e*12 + h16*6 + 2]);
      float2 w2 = *(const float2*)(&wlds[slot][e*12 + h16*6 + 4]);
      float xf[8];
      #pragma unroll
      for (int i=0;i<8;i++) xf[i] = bf2f((unsigned short)cx[i]);
      float wv6[6] = {w0.x,w0.y, w1.x,w1.y, w2.x,w2.y};
      #pragma unroll
      for (int h=0;h<6;h++)
        #pragma unroll
        for (int i=0;i<8;i++) acc[h][i] += wv6[h]*xf[i];
    }
    __builtin_amdgcn_wave_barrier();
  }

  // reduce ss over the 32-lane group (offsets stay inside the group)
  #pragma unroll
  for (int h=0;h<12;h++){
    #pragma unroll
    for (int off=16; off; off>>=1) ss[h] += __shfl_xor(ss[h], off);
  }
  float inv[6];
  #pragma unroll
  for (int h=0;h<6;h++) inv[h] = 1.f / ss[h16*6 + h];

  // ---- epilogue: agg(bf16, LDS) @ W1 per head, two halves of 6 heads ----
  const int wv = tid >> 6, wl = tid & 63;
  const int er = wl & 15, eq = wl >> 4;
  #pragma unroll
  for (int hf = 0; hf < 2; ++hf){
    __syncthreads();   // prev half's MFMA reads complete before overwrite
    if (h16 == hf){
      #pragma unroll
      for (int h = 0; h < 6; ++h){
        ushort8 v;
        #pragma unroll
        for (int i=0;i<8;i++) v[i] = f2bf(acc[h][i]*inv[h]);
        *(ushort8*)(&agg[slot*ROWE + h*F_IN + t16*8]) = v;
      }
    }
    __syncthreads();
    for (int tt = wv; tt < 12; tt += 8){
      int h = tt >> 1, nb = tt & 1;
      int hh = hf*6 + h;
      f32x4 c = {0.f,0.f,0.f,0.f};
      #pragma unroll
      for (int kk=0; kk<4; ++kk){
        bf16x8 af = *(const bf16x8*)(&agg[er*ROWE + h*F_IN + kk*32 + eq*8]);
        bf16x8 bq = *(const bf16x8*)(w1t + (size_t)(hh*32 + nb*16 + er)*F_IN + kk*32 + eq*8);
        c = __builtin_amdgcn_mfma_f32_16x16x32_bf16(af, bq, c, 0,0,0);
      }
      int col = hh*32 + nb*16 + er;
      float bv = bias[col];
      #pragma unroll
      for (int rr=0; rr<4; ++rr){
        int od = blockIdx.x*16 + eq*4 + rr;
        out1[(size_t)od*C1 + col] = f2bf(fmaxf(c[rr] + bv, 0.f));
      }
    }
  }
}

// ---------- per-node attention halves, conv2 ----------
__global__ void a2_kernel(const unsigned short* __restrict__ h2,
    const float* __restrict__ att_src, const float* __restrict__ att_dst,
    float* __restrict__ a_src, float* __restrict__ a_dst){
  int n = blockIdx.x*blockDim.x + threadIdx.x;
  if (n >= N_NODES) return;
  const unsigned short* hp = h2 + (size_t)n*C2;
  float s=0.f, d=0.f;
  #pragma unroll
  for (int k4=0;k4<16;k4++){
    ushort4 v = *(const ushort4*)(hp + k4*4);
    int b = k4*4;
    s += bf2f(v.x)*att_src[b] + bf2f(v.y)*att_src[b+1] + bf2f(v.z)*att_src[b+2] + bf2f(v.w)*att_src[b+3];
    d += bf2f(v.x)*att_dst[b] + bf2f(v.y)*att_dst[b+1] + bf2f(v.z)*att_dst[b+2] + bf2f(v.w)*att_dst[b+3];
  }
  a_src[n]=s; a_dst[n]=d;
}

// ---------- conv2: no-max softmax + aggregation + pool atomics (shfl-only) ----------
// 256 thr = 16 dst/block, 16 lanes/dst (4 feats each); staging lane computes w once.
__global__ __launch_bounds__(256) void agg2s_kernel(const int* __restrict__ rowptr,
    const int* __restrict__ csr, const unsigned short* __restrict__ h2,
    const float* __restrict__ asrc, const float* __restrict__ adst,
    const float* __restrict__ bias, const int* __restrict__ batch,
    float* __restrict__ pool){
  const int tid  = threadIdx.x;
  const int slot = tid >> 4;
  const int t16  = tid & 15;
  const int base = ((tid & 63) >> 4) * 16;
  const int d    = blockIdx.x*16 + slot;
  const int r0 = rowptr[d], r1 = rowptr[d+1];
  const float ad = adst[d];

  float ssp = 0.f;
  float a0=0.f, a1=0.f, a2=0.f, a3=0.f;

  for (int c0 = r0; c0 < r1; c0 += 16){
    int nc = min(16, r1 - c0);
    int s_st = 0; float w_st = 0.f;
    if (t16 < nc){
      s_st = csr[c0 + t16];
      w_st = wexp(lrelu(asrc[s_st] + ad));
      ssp += w_st;
    }
    int sA = __shfl(s_st, base + 0);
    ushort4 xA = *(const ushort4*)(h2 + (size_t)sA*C2 + t16*4);
    ushort4 xB = {0,0,0,0};
    if (nc > 1){
      int sB = __shfl(s_st, base + 1);
      xB = *(const ushort4*)(h2 + (size_t)sB*C2 + t16*4);
    }
    for (int e = 0; e < nc; ++e){
      ushort4 cx = xA;
      xA = xB;
      if (e + 2 < nc){
        int sN = __shfl(s_st, base + e + 2);
        xB = *(const ushort4*)(h2 + (size_t)sN*C2 + t16*4);
      }
      float w = __shfl(w_st, base + e);
      a0 += w*bf2f(cx.x);
      a1 += w*bf2f(cx.y);
      a2 += w*bf2f(cx.z);
      a3 += w*bf2f(cx.w);
    }
  }
  #pragma unroll
  for (int off=8; off; off>>=1) ssp += __shfl_xor(ssp, off);
  float inv = 1.f / ssp;
  int g = batch[d];
  int fb = t16*4;
  atomicAdd(&pool[g*C2 + fb+0], a0*inv + bias[fb+0]);
  atomicAdd(&pool[g*C2 + fb+1], a1*inv + bias[fb+1]);
  atomicAdd(&pool[g*C2 + fb+2], a2*inv + bias[fb+2]);
  atomicAdd(&pool[g*C2 + fb+3], a3*inv + bias[fb+3]);
}

__global__ void finalize_kernel(const float* __restrict__ sums, const int* __restrict__ cnt,
                                float* __restrict__ out){
  int i = blockIdx.x*blockDim.x + threadIdx.x;
  if (i >= G_GRAPHS*C2) return;
  int g = i >> 6;
  out[i] = sums[i] / fmaxf((float)cnt[g], 1.f);
}

// ---------- launch ----------
extern "C" void kernel_launch(void* const* d_in, const int* in_sizes, int n_in,
                              void* d_out, int out_size, void* d_ws, size_t ws_size,
                              hipStream_t stream) {
  const float* x        = (const float*)d_in[0];
  const int*   ei       = (const int*)  d_in[1];
  const int*   batch    = (const int*)  d_in[2];
  const float* W1       = (const float*)d_in[3];
  const float* att_src1 = (const float*)d_in[4];
  const float* att_dst1 = (const float*)d_in[5];
  const float* bias1    = (const float*)d_in[6];
  const float* W2       = (const float*)d_in[7];
  const float* att_src2 = (const float*)d_in[8];
  const float* att_dst2 = (const float*)d_in[9];
  const float* bias2    = (const float*)d_in[10];
  float* out = (float*)d_out;

  char* ws = (char*)d_ws;
  size_t o = 0;
  auto alloc = [&](size_t bytes)->size_t{ size_t r=o; o=(o+bytes+255)&~(size_t)255; return r; };

  size_t xb_o     = alloc((size_t)N_NODES*F_IN*2);   // 12.8 MB
  size_t w1t_o    = alloc((size_t)C1*F_IN*2);
  size_t w2t_o    = alloc((size_t)C2*C1*2);
  size_t wab_o    = alloc((size_t)32*F_IN*2);
  size_t asd_o    = alloc((size_t)N_NODES*32*4);     // 6.4 MB (src:0-11, dst:12-23)
  size_t out1_o   = alloc((size_t)N_NODES*C1*2);     // 38.4 MB
  size_t h2_o     = alloc((size_t)N_NODES*C2*2);     // 6.4 MB
  size_t asrc2_o  = alloc((size_t)N_NODES*4);
  size_t adst2_o  = alloc((size_t)N_NODES*4);
  size_t zero_beg = o;
  size_t counts_o = alloc((size_t)N_NODES*4);
  size_t pool_o   = alloc((size_t)G_GRAPHS*C2*4);
  size_t cnt_o    = alloc((size_t)G_GRAPHS*4);
  size_t zero_end = o;
  size_t rowptr_o = alloc((size_t)(N_NODES+1)*4);
  size_t bsum_o   = alloc((size_t)NBLK_SCAN*4);
  size_t cursor_o = alloc((size_t)N_NODES*4);
  size_t csr_o    = alloc((size_t)ETOT*4);

  unsigned short* xb    = (unsigned short*)(ws + xb_o);
  unsigned short* w1t   = (unsigned short*)(ws + w1t_o);
  unsigned short* w2t   = (unsigned short*)(ws + w2t_o);
  unsigned short* wab   = (unsigned short*)(ws + wab_o);
  float* asd    = (float*)(ws + asd_o);
  unsigned short* out1b = (unsigned short*)(ws + out1_o);
  unsigned short* h2b   = (unsigned short*)(ws + h2_o);
  float* asrc2  = (float*)(ws + asrc2_o);
  float* adst2  = (float*)(ws + adst2_o);
  int*   counts = (int*)  (ws + counts_o);
  float* poolf  = (float*)(ws + pool_o);
  int*   cnt    = (int*)  (ws + cnt_o);
  int*   rowptr = (int*)  (ws + rowptr_o);
  int*   bsum   = (int*)  (ws + bsum_o);
  int*   cursor = (int*)  (ws + cursor_o);
  int*   csrsrc = (int*)  (ws + csr_o);

  hipMemsetAsync(ws + zero_beg, 0, zero_end - zero_beg, stream);

  const int TPB = 256;

  // prep (cast x, transpose W1/W2, wAb) in one kernel
  prep_kernel<<<B_CAST + B_W1 + B_W2 + B_WAB, TPB, 0, stream>>>(
      x, W1, W2, att_src1, att_dst1, xb, w1t, w2t, wab);

  // CSR build (+ batch histogram folded into count)
  count_cnt_kernel<<<EGRID + NGRID, TPB, 0, stream>>>(ei, batch, counts, cnt);
  scan_pass1<<<NBLK_SCAN, SCAN_B, 0, stream>>>(counts, rowptr, bsum);
  scan_pass3<<<(N_NODES + 1 + 255)/256, TPB, 0, stream>>>(rowptr, bsum, cursor);
  scatter_kernel<<<EGRID, TPB, 0, stream>>>(ei, cursor, csrsrc);

  // conv1: logits GEMM -> fused no-max softmax + agg + MFMA transform
  gemm_mfma<64,32,32,16,true><<<dim3((N_NODES+63)/64, 1), 256, 0, stream>>>(xb, wab, asd, N_NODES, 32, F_IN);
  agg1s_kernel<<<N_NODES/16, 512, 0, stream>>>(rowptr, csrsrc, xb, asd, w1t, bias1, out1b);

  // conv2
  gemm_mfma<64,64,32,32,false><<<dim3((N_NODES+63)/64, 1), 256, 0, stream>>>(out1b, w2t, h2b, N_NODES, C2, C1);
  a2_kernel<<<(N_NODES + TPB-1)/TPB, TPB, 0, stream>>>(h2b, att_src2, att_dst2, asrc2, adst2);
  agg2s_kernel<<<(N_NODES+15)/16, TPB, 0, stream>>>(rowptr, csrsrc, h2b, asrc2, adst2, bias2, batch, poolf);

  // pool finalize
  finalize_kernel<<<(G_GRAPHS*C2 + TPB-1)/TPB, TPB, 0, stream>>>(poolf, cnt, out);
}

// Round 10
// 424.352 us; speedup vs baseline: 1.2526x; 1.0419x over previous
//
#include <hip/hip_runtime.h>

#define N_NODES 50000
#define N_EDGES 800000
#define ETOT (N_EDGES + N_NODES)   // 850000
#define G_GRAPHS 256
#define F_IN 128
#define H1 12
#define D1 32
#define C1 (H1*D1)   // 384
#define C2 64
#define NEG 0.2f
#define SCAN_B 1024
#define NBLK_SCAN ((N_NODES + SCAN_B - 1)/SCAN_B)   // 49

using bf16x8  = __attribute__((ext_vector_type(8))) short;
using ushort8 = __attribute__((ext_vector_type(8))) unsigned short;
using f32x4   = __attribute__((ext_vector_type(4))) float;

__device__ __forceinline__ float lrelu(float x){ return x > 0.f ? x : NEG*x; }
__device__ __forceinline__ unsigned short f2bf(float f){
  unsigned u = __float_as_uint(f);
  u += 0x7fffu + ((u >> 16) & 1u);
  return (unsigned short)(u >> 16);
}
__device__ __forceinline__ float bf2f(unsigned short h){
  return __uint_as_float(((unsigned)h) << 16);
}
// exp without max-subtraction; clamp is overflow guard only (never hit, |l|<=~8 here)
__device__ __forceinline__ float wexp(float l){ return __expf(fminf(l, 30.f)); }

// ---------- merged prep: cast x, transpose W1/W2, build wAb ----------
#define B_CAST ((N_NODES*F_IN/4 + 255)/256)   // 6250
#define B_W1   ((F_IN*C1 + 255)/256)          // 192
#define B_W2   ((C1*C2 + 255)/256)            // 96
#define B_WAB  ((32*F_IN + 255)/256)          // 16
__global__ void prep_kernel(const float* __restrict__ x, const float* __restrict__ W1,
    const float* __restrict__ W2, const float* __restrict__ att_src,
    const float* __restrict__ att_dst, unsigned short* __restrict__ xb,
    unsigned short* __restrict__ w1t, unsigned short* __restrict__ w2t,
    unsigned short* __restrict__ wAb){
  int b = blockIdx.x, tid = threadIdx.x;
  if (b < B_CAST){
    int base = (b*256 + tid)*4;
    if (base >= N_NODES*F_IN) return;
    float4 v = *(const float4*)(x + base);
    ushort4 o; o.x=f2bf(v.x); o.y=f2bf(v.y); o.z=f2bf(v.z); o.w=f2bf(v.w);
    *(ushort4*)(xb + base) = o;
  } else if (b < B_CAST + B_W1){
    int i = (b - B_CAST)*256 + tid;
    if (i >= F_IN*C1) return;
    int n = i / F_IN, k = i % F_IN;
    w1t[i] = f2bf(W1[(size_t)k*C1 + n]);
  } else if (b < B_CAST + B_W1 + B_W2){
    int i = (b - B_CAST - B_W1)*256 + tid;
    if (i >= C1*C2) return;
    int n = i / C1, k = i % C1;
    w2t[i] = f2bf(W2[(size_t)k*C2 + n]);
  } else {
    int i = (b - B_CAST - B_W1 - B_W2)*256 + tid;
    if (i >= 32*F_IN) return;
    int c = i >> 7, k = i & 127;
    float v = 0.f;
    if (c < 12){
      #pragma unroll
      for (int dd=0; dd<D1; ++dd) v += W1[(size_t)k*C1 + c*D1 + dd] * att_src[c*D1 + dd];
    } else if (c < 24){
      int h = c - 12;
      #pragma unroll
      for (int dd=0; dd<D1; ++dd) v += W1[(size_t)k*C1 + h*D1 + dd] * att_dst[h*D1 + dd];
    }
    wAb[i] = f2bf(v);
  }
}

// ---------- bf16 MFMA GEMM (logits): C[M][N] = A[M][K] @ Bt[N][K]^T ----------
template<int BM,int BN,int WM,int WN,bool F32OUT>
__global__ __launch_bounds__(256) void gemm_mfma(const unsigned short* __restrict__ A,
    const unsigned short* __restrict__ Bt, void* __restrict__ Cv,
    int M, int N, int K){
  constexpr int BK = 32;
  __shared__ unsigned short As2[4][BM][8];
  __shared__ unsigned short Bs2[4][BN][8];
  const int tid  = threadIdx.x;
  const int wid  = tid >> 6, lane = tid & 63;
  constexpr int NWX = BN / WN;
  const int wrow = (wid / NWX) * WM, wcol = (wid % NWX) * WN;
  constexpr int MR = WM/16, NR = WN/16;
  const int row0 = blockIdx.x * BM, col0 = blockIdx.y * BN;
  const int r = lane & 15, koct = lane >> 4;
  f32x4 acc[MR][NR];
  #pragma unroll
  for (int m=0;m<MR;m++)
    #pragma unroll
    for (int n=0;n<NR;n++) acc[m][n] = f32x4{0.f,0.f,0.f,0.f};

  for (int k0 = 0; k0 < K; k0 += BK){
    for (int s = tid; s < BM*8; s += 256){
      int rr = s >> 3, cc = (s & 7) * 4;
      int gr = row0 + rr;
      ushort4 v = (gr < M) ? *(const ushort4*)(A + (size_t)gr*K + k0 + cc)
                           : ushort4{0,0,0,0};
      *(ushort4*)(&As2[cc>>3][rr][cc&7]) = v;
    }
    for (int s = tid; s < BN*8; s += 256){
      int rr = s >> 3, cc = (s & 7) * 4;
      ushort4 v = *(const ushort4*)(Bt + (size_t)(col0+rr)*K + k0 + cc);
      *(ushort4*)(&Bs2[cc>>3][rr][cc&7]) = v;
    }
    __syncthreads();
    bf16x8 af[MR], bq[NR];
    #pragma unroll
    for (int m=0;m<MR;m++) af[m] = *(const bf16x8*)(&As2[koct][wrow + m*16 + r][0]);
    #pragma unroll
    for (int n=0;n<NR;n++) bq[n] = *(const bf16x8*)(&Bs2[koct][wcol + n*16 + r][0]);
    #pragma unroll
    for (int m=0;m<MR;m++)
      #pragma unroll
      for (int n=0;n<NR;n++)
        acc[m][n] = __builtin_amdgcn_mfma_f32_16x16x32_bf16(af[m], bq[n], acc[m][n], 0,0,0);
    __syncthreads();
  }
  #pragma unroll
  for (int m=0;m<MR;m++){
    #pragma unroll
    for (int rr=0; rr<4; rr++){
      int grow = row0 + wrow + m*16 + koct*4 + rr;
      if (grow < M){
        #pragma unroll
        for (int n=0;n<NR;n++){
          if constexpr (F32OUT)
            ((float*)Cv)[(size_t)grow*N + col0 + wcol + n*16 + r] = acc[m][n][rr];
          else
            ((unsigned short*)Cv)[(size_t)grow*N + col0 + wcol + n*16 + r] = f2bf(acc[m][n][rr]);
        }
      }
    }
  }
}

// ---------- CSR build ----------
#define EGRID ((ETOT + 255)/256)          // 3321
#define NGRID ((N_NODES + 255)/256)       // 196
__global__ void count_cnt_kernel(const int* __restrict__ ei, const int* __restrict__ batch,
                                 int* __restrict__ counts, int* __restrict__ cnt){
  if ((int)blockIdx.x < EGRID){
    int e = blockIdx.x*256 + threadIdx.x;
    if (e >= ETOT) return;
    int d = (e < N_EDGES) ? ei[N_EDGES + e] : (e - N_EDGES);
    atomicAdd(&counts[d], 1);
  } else {
    int n = (blockIdx.x - EGRID)*256 + threadIdx.x;
    if (n < N_NODES) atomicAdd(&cnt[batch[n]], 1);
  }
}
__global__ __launch_bounds__(SCAN_B) void scan_pass1(const int* __restrict__ counts,
    int* __restrict__ excl, int* __restrict__ bsum){
  __shared__ int sdata[SCAN_B];
  int i = blockIdx.x*SCAN_B + threadIdx.x;
  int v = (i < N_NODES) ? counts[i] : 0;
  sdata[threadIdx.x] = v;
  __syncthreads();
  for (int off=1; off<SCAN_B; off<<=1){
    int t = (threadIdx.x >= off) ? sdata[threadIdx.x-off] : 0;
    __syncthreads();
    sdata[threadIdx.x] += t;
    __syncthreads();
  }
  if (i < N_NODES) excl[i] = sdata[threadIdx.x] - v;
  if (threadIdx.x == SCAN_B-1) bsum[blockIdx.x] = sdata[SCAN_B-1];
}
__global__ void scan_pass3(int* __restrict__ rowptr, const int* __restrict__ bsum,
                           int* __restrict__ cursor){
  __shared__ int carry_s;
  int sblk = blockIdx.x >> 2;
  if (threadIdx.x == 0){
    int c = 0;
    for (int b=0; b<sblk; ++b) c += bsum[b];
    carry_s = c;
  }
  __syncthreads();
  int i = blockIdx.x*256 + (int)threadIdx.x;
  if (i < N_NODES){
    int r = rowptr[i] + carry_s;
    rowptr[i] = r; cursor[i] = r;
  }
  if (i == N_NODES) rowptr[N_NODES] = ETOT;
}
__global__ void scatter_kernel(const int* __restrict__ ei, int* __restrict__ cursor,
                               int* __restrict__ csr_src){
  int e = blockIdx.x*blockDim.x + threadIdx.x;
  if (e >= ETOT) return;
  int s, d;
  if (e < N_EDGES){ s = ei[e]; d = ei[N_EDGES + e]; } else { s = d = e - N_EDGES; }
  int slot = atomicAdd(&cursor[d], 1);
  csr_src[slot] = s;
}

// ---------- conv1 grand-fused: no-max softmax + x-space agg + W1 MFMA + ReLU
//            + partial gemm2 (h2 = relu_out1 @ W2) + a2 dots. out1 never materialized.
// 256 thr = 4 waves = 16 dst/block, 16 lanes/dst (R8-proven loop structure).
__global__ __launch_bounds__(256) void agg1g_kernel(const int* __restrict__ rowptr,
    const int* __restrict__ csr, const unsigned short* __restrict__ xb,
    const float* __restrict__ asd, const unsigned short* __restrict__ w1t,
    const unsigned short* __restrict__ w2t, const float* __restrict__ bias1,
    const float* __restrict__ att_src2, const float* __restrict__ att_dst2,
    unsigned short* __restrict__ h2, float* __restrict__ asrc2, float* __restrict__ adst2){
  constexpr int ROWE = 6*F_IN + 8;            // 776 ushorts, per-slot agg row (6 heads)
  constexpr int WROW = 16*12 + 4;             // 196 floats, per-slot weight row
  constexpr int ROWR = 192 + 8;               // 200 ushorts, relu-out1 half-row
  __shared__ unsigned short agg[16*ROWE];     // 24832 B
  __shared__ float wlds[16][WROW];            // 12544 B (reused as reluLDS + a2-red)

  unsigned short* reluLDS = (unsigned short*)&wlds[0][0];   // 16 x ROWR ushorts = 6400 B
  float* red = (float*)&agg[0];                              // a2 reduce scratch (reused at end)

  const int tid  = threadIdx.x;
  const int slot = tid >> 4;                  // 0..15 dst in block
  const int t16  = tid & 15;
  const int base = ((tid & 63) >> 4) * 16;    // 16-lane group base within wave
  const int d    = blockIdx.x*16 + slot;
  const int r0 = rowptr[d], r1 = rowptr[d+1];

  float4 ad0 = *(const float4*)(asd + (size_t)d*32 + 12);
  float4 ad1 = *(const float4*)(asd + (size_t)d*32 + 16);
  float4 ad2 = *(const float4*)(asd + (size_t)d*32 + 20);
  float ad[12] = {ad0.x,ad0.y,ad0.z,ad0.w, ad1.x,ad1.y,ad1.z,ad1.w, ad2.x,ad2.y,ad2.z,ad2.w};

  float acc[12][8];
  #pragma unroll
  for (int h=0;h<12;h++)
    #pragma unroll
    for (int i=0;i<8;i++) acc[h][i] = 0.f;
  float ss[12];
  #pragma unroll
  for (int h=0;h<12;h++) ss[h] = 0.f;

  // ---- main loop: 16-edge chunks; staging lane computes w[12] inline (no-max) ----
  for (int c0 = r0; c0 < r1; c0 += 16){
    int nc = min(16, r1 - c0);
    int s_st = 0;
    if (t16 < nc){
      int j = c0 + t16;
      s_st = csr[j];
      float4 s0 = *(const float4*)(asd + (size_t)s_st*32);
      float4 s1 = *(const float4*)(asd + (size_t)s_st*32 + 4);
      float4 s2 = *(const float4*)(asd + (size_t)s_st*32 + 8);
      float as[12] = {s0.x,s0.y,s0.z,s0.w, s1.x,s1.y,s1.z,s1.w, s2.x,s2.y,s2.z,s2.w};
      float w[12];
      #pragma unroll
      for (int h=0;h<12;h++){ w[h] = wexp(lrelu(as[h] + ad[h])); ss[h] += w[h]; }
      *(float4*)(&wlds[slot][t16*12 + 0]) = float4{w[0],w[1],w[2],w[3]};
      *(float4*)(&wlds[slot][t16*12 + 4]) = float4{w[4],w[5],w[6],w[7]};
      *(float4*)(&wlds[slot][t16*12 + 8]) = float4{w[8],w[9],w[10],w[11]};
    }
    __builtin_amdgcn_wave_barrier();
    int sA = __shfl(s_st, base + 0);
    ushort8 xA = *(const ushort8*)(xb + (size_t)sA*F_IN + t16*8);
    ushort8 xB = {0,0,0,0,0,0,0,0};
    if (nc > 1){
      int sB = __shfl(s_st, base + 1);
      xB = *(const ushort8*)(xb + (size_t)sB*F_IN + t16*8);
    }
    for (int e = 0; e < nc; ++e){
      ushort8 cx = xA;
      xA = xB;
      if (e + 2 < nc){
        int sN = __shfl(s_st, base + e + 2);
        xB = *(const ushort8*)(xb + (size_t)sN*F_IN + t16*8);
      }
      float4 w0 = *(const float4*)(&wlds[slot][e*12 + 0]);
      float4 w1 = *(const float4*)(&wlds[slot][e*12 + 4]);
      float4 w2 = *(const float4*)(&wlds[slot][e*12 + 8]);
      float xf[8];
      #pragma unroll
      for (int i=0;i<8;i++) xf[i] = bf2f((unsigned short)cx[i]);
      float w[12] = {w0.x,w0.y,w0.z,w0.w, w1.x,w1.y,w1.z,w1.w, w2.x,w2.y,w2.z,w2.w};
      #pragma unroll
      for (int h=0;h<12;h++)
        #pragma unroll
        for (int i=0;i<8;i++) acc[h][i] += w[h]*xf[i];
    }
    __builtin_amdgcn_wave_barrier();
  }

  // reduce ss over 16-lane group; normalize factors
  #pragma unroll
  for (int h=0;h<12;h++){
    #pragma unroll
    for (int off=8; off; off>>=1) ss[h] += __shfl_xor(ss[h], off);
  }
  float inv[12];
  #pragma unroll
  for (int h=0;h<12;h++) inv[h] = 1.f / ss[h];

  // ---- epilogue: per 6-head half: agg->LDS, W1-MFMA + bias + ReLU -> reluLDS,
  //      then partial gemm2 (K=192) accumulating h2 in regs ----
  const int wv = tid >> 6, wl = tid & 63;
  const int er = wl & 15, eq = wl >> 4;
  f32x4 h2acc = {0.f,0.f,0.f,0.f};
  #pragma unroll
  for (int hf = 0; hf < 2; ++hf){
    __syncthreads();   // main loop done (hf=0) / prev half's reluLDS+agg reads done (hf=1)
    #pragma unroll
    for (int h = 0; h < 6; ++h){
      int hh = hf*6 + h;
      ushort8 v;
      #pragma unroll
      for (int i=0;i<8;i++) v[i] = f2bf(acc[hh][i]*inv[hh]);
      *(ushort8*)(&agg[slot*ROWE + h*F_IN + t16*8]) = v;
    }
    __syncthreads();
    // W1 transform: 12 tiles (192 cols) over 4 waves; bias+ReLU -> reluLDS
    for (int tt = wv; tt < 12; tt += 4){
      int h = tt >> 1, nb = tt & 1;
      int hh = hf*6 + h;
      f32x4 c = {0.f,0.f,0.f,0.f};
      #pragma unroll
      for (int kk=0; kk<4; ++kk){
        bf16x8 af = *(const bf16x8*)(&agg[er*ROWE + h*F_IN + kk*32 + eq*8]);
        bf16x8 bq = *(const bf16x8*)(w1t + (size_t)(hh*32 + nb*16 + er)*F_IN + kk*32 + eq*8);
        c = __builtin_amdgcn_mfma_f32_16x16x32_bf16(af, bq, c, 0,0,0);
      }
      int lcol = tt*16 + er;                    // local col within half (0..191)
      float bv = bias1[hf*192 + lcol];
      #pragma unroll
      for (int rr=0; rr<4; ++rr){
        int row = eq*4 + rr;                    // dst row 0..15
        reluLDS[row*ROWR + lcol] = f2bf(fmaxf(c[rr] + bv, 0.f));
      }
    }
    __syncthreads();
    // partial gemm2: wave wv owns h2 cols [wv*16, wv*16+16), K=192 this half
    #pragma unroll
    for (int kk=0; kk<6; ++kk){
      bf16x8 af = *(const bf16x8*)(&reluLDS[er*ROWR + kk*32 + eq*8]);
      bf16x8 bq = *(const bf16x8*)(w2t + (size_t)(wv*16 + er)*C1 + hf*192 + kk*32 + eq*8);
      h2acc = __builtin_amdgcn_mfma_f32_16x16x32_bf16(af, bq, h2acc, 0,0,0);
    }
  }
  __syncthreads();   // reluLDS/agg reads done; agg region reusable as red

  // ---- write h2 (bf16) + a2 dots ----
  float attS = att_src2[wv*16 + er];
  float attD = att_dst2[wv*16 + er];
  float psum[4], pdum[4];
  #pragma unroll
  for (int rr=0; rr<4; ++rr){
    int row = eq*4 + rr;
    int gn = blockIdx.x*16 + row;
    h2[(size_t)gn*C2 + wv*16 + er] = f2bf(h2acc[rr]);
    psum[rr] = h2acc[rr]*attS;
    pdum[rr] = h2acc[rr]*attD;
  }
  // reduce over er (16 cols of this wave)
  #pragma unroll
  for (int rr=0; rr<4; ++rr){
    #pragma unroll
    for (int off=8; off; off>>=1){
      psum[rr] += __shfl_xor(psum[rr], off);
      pdum[rr] += __shfl_xor(pdum[rr], off);
    }
  }
  if (er == 0){
    #pragma unroll
    for (int rr=0; rr<4; ++rr){
      int row = eq*4 + rr;
      red[(wv*16 + row)*2 + 0] = psum[rr];
      red[(wv*16 + row)*2 + 1] = pdum[rr];
    }
  }
  __syncthreads();
  if (tid < 32){
    int row = tid >> 1, which = tid & 1;
    float v = red[row*2+which] + red[(16+row)*2+which] + red[(32+row)*2+which] + red[(48+row)*2+which];
    int gn = blockIdx.x*16 + row;
    if (which == 0) asrc2[gn] = v; else adst2[gn] = v;
  }
}

// ---------- conv2: no-max softmax + aggregation + pool atomics ----------
__global__ __launch_bounds__(256) void agg2s_kernel(const int* __restrict__ rowptr,
    const int* __restrict__ csr, const unsigned short* __restrict__ h2,
    const float* __restrict__ asrc, const float* __restrict__ adst,
    const float* __restrict__ bias, const int* __restrict__ batch,
    float* __restrict__ pool){
  const int tid  = threadIdx.x;
  const int slot = tid >> 4;
  const int t16  = tid & 15;
  const int base = ((tid & 63) >> 4) * 16;
  const int d    = blockIdx.x*16 + slot;
  const int r0 = rowptr[d], r1 = rowptr[d+1];
  const float ad = adst[d];

  float ssp = 0.f;
  float a0=0.f, a1=0.f, a2=0.f, a3=0.f;

  for (int c0 = r0; c0 < r1; c0 += 16){
    int nc = min(16, r1 - c0);
    int s_st = 0; float w_st = 0.f;
    if (t16 < nc){
      s_st = csr[c0 + t16];
      w_st = wexp(lrelu(asrc[s_st] + ad));
      ssp += w_st;
    }
    int sA = __shfl(s_st, base + 0);
    ushort4 xA = *(const ushort4*)(h2 + (size_t)sA*C2 + t16*4);
    ushort4 xB = {0,0,0,0};
    if (nc > 1){
      int sB = __shfl(s_st, base + 1);
      xB = *(const ushort4*)(h2 + (size_t)sB*C2 + t16*4);
    }
    for (int e = 0; e < nc; ++e){
      ushort4 cx = xA;
      xA = xB;
      if (e + 2 < nc){
        int sN = __shfl(s_st, base + e + 2);
        xB = *(const ushort4*)(h2 + (size_t)sN*C2 + t16*4);
      }
      float w = __shfl(w_st, base + e);
      a0 += w*bf2f(cx.x);
      a1 += w*bf2f(cx.y);
      a2 += w*bf2f(cx.z);
      a3 += w*bf2f(cx.w);
    }
  }
  #pragma unroll
  for (int off=8; off; off>>=1) ssp += __shfl_xor(ssp, off);
  float inv = 1.f / ssp;
  int g = batch[d];
  int fb = t16*4;
  atomicAdd(&pool[g*C2 + fb+0], a0*inv + bias[fb+0]);
  atomicAdd(&pool[g*C2 + fb+1], a1*inv + bias[fb+1]);
  atomicAdd(&pool[g*C2 + fb+2], a2*inv + bias[fb+2]);
  atomicAdd(&pool[g*C2 + fb+3], a3*inv + bias[fb+3]);
}

__global__ void finalize_kernel(const float* __restrict__ sums, const int* __restrict__ cnt,
                                float* __restrict__ out){
  int i = blockIdx.x*blockDim.x + threadIdx.x;
  if (i >= G_GRAPHS*C2) return;
  int g = i >> 6;
  out[i] = sums[i] / fmaxf((float)cnt[g], 1.f);
}

// ---------- launch ----------
extern "C" void kernel_launch(void* const* d_in, const int* in_sizes, int n_in,
                              void* d_out, int out_size, void* d_ws, size_t ws_size,
                              hipStream_t stream) {
  const float* x        = (const float*)d_in[0];
  const int*   ei       = (const int*)  d_in[1];
  const int*   batch    = (const int*)  d_in[2];
  const float* W1       = (const float*)d_in[3];
  const float* att_src1 = (const float*)d_in[4];
  const float* att_dst1 = (const float*)d_in[5];
  const float* bias1    = (const float*)d_in[6];
  const float* W2       = (const float*)d_in[7];
  const float* att_src2 = (const float*)d_in[8];
  const float* att_dst2 = (const float*)d_in[9];
  const float* bias2    = (const float*)d_in[10];
  float* out = (float*)d_out;

  char* ws = (char*)d_ws;
  size_t o = 0;
  auto alloc = [&](size_t bytes)->size_t{ size_t r=o; o=(o+bytes+255)&~(size_t)255; return r; };

  size_t xb_o     = alloc((size_t)N_NODES*F_IN*2);   // 12.8 MB
  size_t w1t_o    = alloc((size_t)C1*F_IN*2);
  size_t w2t_o    = alloc((size_t)C2*C1*2);
  size_t wab_o    = alloc((size_t)32*F_IN*2);
  size_t asd_o    = alloc((size_t)N_NODES*32*4);     // 6.4 MB (src:0-11, dst:12-23)
  size_t h2_o     = alloc((size_t)N_NODES*C2*2);     // 6.4 MB
  size_t asrc2_o  = alloc((size_t)N_NODES*4);
  size_t adst2_o  = alloc((size_t)N_NODES*4);
  size_t zero_beg = o;
  size_t counts_o = alloc((size_t)N_NODES*4);
  size_t pool_o   = alloc((size_t)G_GRAPHS*C2*4);
  size_t cnt_o    = alloc((size_t)G_GRAPHS*4);
  size_t zero_end = o;
  size_t rowptr_o = alloc((size_t)(N_NODES+1)*4);
  size_t bsum_o   = alloc((size_t)NBLK_SCAN*4);
  size_t cursor_o = alloc((size_t)N_NODES*4);
  size_t csr_o    = alloc((size_t)ETOT*4);

  unsigned short* xb    = (unsigned short*)(ws + xb_o);
  unsigned short* w1t   = (unsigned short*)(ws + w1t_o);
  unsigned short* w2t   = (unsigned short*)(ws + w2t_o);
  unsigned short* wab   = (unsigned short*)(ws + wab_o);
  float* asd    = (float*)(ws + asd_o);
  unsigned short* h2b   = (unsigned short*)(ws + h2_o);
  float* asrc2  = (float*)(ws + asrc2_o);
  float* adst2  = (float*)(ws + adst2_o);
  int*   counts = (int*)  (ws + counts_o);
  float* poolf  = (float*)(ws + pool_o);
  int*   cnt    = (int*)  (ws + cnt_o);
  int*   rowptr = (int*)  (ws + rowptr_o);
  int*   bsum   = (int*)  (ws + bsum_o);
  int*   cursor = (int*)  (ws + cursor_o);
  int*   csrsrc = (int*)  (ws + csr_o);

  hipMemsetAsync(ws + zero_beg, 0, zero_end - zero_beg, stream);

  const int TPB = 256;

  // prep
  prep_kernel<<<B_CAST + B_W1 + B_W2 + B_WAB, TPB, 0, stream>>>(
      x, W1, W2, att_src1, att_dst1, xb, w1t, w2t, wab);

  // CSR build
  count_cnt_kernel<<<EGRID + NGRID, TPB, 0, stream>>>(ei, batch, counts, cnt);
  scan_pass1<<<NBLK_SCAN, SCAN_B, 0, stream>>>(counts, rowptr, bsum);
  scan_pass3<<<(N_NODES + 1 + 255)/256, TPB, 0, stream>>>(rowptr, bsum, cursor);
  scatter_kernel<<<EGRID, TPB, 0, stream>>>(ei, cursor, csrsrc);

  // conv1 logits
  gemm_mfma<64,32,32,16,true><<<dim3((N_NODES+63)/64, 1), 256, 0, stream>>>(xb, wab, asd, N_NODES, 32, F_IN);
  // conv1+conv2-linear grand fusion
  agg1g_kernel<<<N_NODES/16, 256, 0, stream>>>(rowptr, csrsrc, xb, asd, w1t, w2t,
                                               bias1, att_src2, att_dst2, h2b, asrc2, adst2);
  // conv2 aggregation + pool
  agg2s_kernel<<<(N_NODES+15)/16, TPB, 0, stream>>>(rowptr, csrsrc, h2b, asrc2, adst2, bias2, batch, poolf);

  // pool finalize
  finalize_kernel<<<(G_GRAPHS*C2 + TPB-1)/TPB, TPB, 0, stream>>>(poolf, cnt, out);
}